// Round 11
// baseline (56.161 us; speedup 1.0000x reference)
//
#include <hip/hip_runtime.h>
#include <math.h>

namespace {
constexpr int NV = 3;    // views
constexpr int NC = 16;   // channels
constexpr int ND = 32;   // depths
constexpr int NH = 256;
constexpr int NW = 320;
constexpr int HW = NH * NW;       // 81920
#define SYM(i, j) ((i) * 4 + (j) - (i) * ((i) + 1) / 2)
}

// ---------------------------------------------------------------------------
// Setup: proj_v = P_v @ inv(P_0); store rot(9)+trans(3) per src view.
// ---------------------------------------------------------------------------
__global__ void proj_setup_kernel(const float* __restrict__ pm,
                                  float* __restrict__ mats) {
    if (threadIdx.x != 0 || blockIdx.x != 0) return;
    float P[NV][4][4];
    for (int v = 0; v < NV; ++v) {
        const float* E = pm + v * 2 * 16;
        const float* K = pm + v * 2 * 16 + 16;
        for (int i = 0; i < 4; ++i)
            for (int j = 0; j < 4; ++j)
                P[v][i][j] = E[i * 4 + j];
        for (int i = 0; i < 3; ++i)
            for (int j = 0; j < 4; ++j) {
                float acc = 0.f;
                for (int k = 0; k < 3; ++k) acc += K[i * 4 + k] * E[k * 4 + j];
                P[v][i][j] = acc;
            }
    }
    float A[4][8];
    for (int i = 0; i < 4; ++i)
        for (int j = 0; j < 4; ++j) {
            A[i][j] = P[0][i][j];
            A[i][j + 4] = (i == j) ? 1.f : 0.f;
        }
    for (int col = 0; col < 4; ++col) {
        int piv = col;
        float best = fabsf(A[col][col]);
        for (int r = col + 1; r < 4; ++r) {
            float av = fabsf(A[r][col]);
            if (av > best) { best = av; piv = r; }
        }
        if (piv != col)
            for (int j = 0; j < 8; ++j) {
                float t = A[col][j]; A[col][j] = A[piv][j]; A[piv][j] = t;
            }
        float inv = 1.f / A[col][col];
        for (int j = 0; j < 8; ++j) A[col][j] *= inv;
        for (int r = 0; r < 4; ++r) {
            if (r == col) continue;
            float f = A[r][col];
            if (f != 0.f)
                for (int j = 0; j < 8; ++j) A[r][j] -= f * A[col][j];
        }
    }
    float Inv[4][4];
    for (int i = 0; i < 4; ++i)
        for (int j = 0; j < 4; ++j) Inv[i][j] = A[i][j + 4];

    for (int v = 1; v < NV; ++v) {
        float M[4][4];
        for (int i = 0; i < 4; ++i)
            for (int j = 0; j < 4; ++j) {
                float acc = 0.f;
                for (int k = 0; k < 4; ++k) acc += P[v][i][k] * Inv[k][j];
                M[i][j] = acc;
            }
        float* o = mats + (v - 1) * 12;
        for (int i = 0; i < 3; ++i)
            for (int j = 0; j < 3; ++j) o[i * 3 + j] = M[i][j];
        for (int i = 0; i < 3; ++i) o[9 + i] = M[i][3];
    }
}

// ---------------------------------------------------------------------------
// R11: FULLY FUSED per-pixel kernel. stats (145 coherent gathers -> 45
// quad-form coefficients) + 32 depth evals (divs batched 4-wide, weights-only
// fast path) + in-register softmax + depth/conf regression + direct writes.
// Eliminates ALL intermediate traffic (R10 paid: coef 14.7MB w + ~59MB r,
// cost 10.5MB w + 10.5MB r, plus 2 extra launches). 1280 single-wave blocks;
// occupancy ~1.25-2 waves/SIMD is intentional -- the thread body is a long
// independent ILP chain (the quad-form made depth evals load-free).
// All register arrays statically indexed (R7 lesson). IEEE div for px,py.
// Slow path (per-lane exact regather) guards generic inputs, execz-skipped.
// ---------------------------------------------------------------------------
__global__ __launch_bounds__(64) void fused_kernel(
    const float* __restrict__ feats,   // [V][C][HW]
    const float* __restrict__ dvals,   // [D][HW]
    const float* __restrict__ wreg,    // [C]
    const float* __restrict__ mats,    // [2][12]
    float* __restrict__ out)           // depth[HW] | conf[HW] | prob[D][HW]
{
    const unsigned n = blockIdx.x * 64u + threadIdx.x;
    const int y = (int)(n / NW);
    const int x = (int)(n - (unsigned)y * NW);
    const float fx = (float)x, fy = (float)y;
    const unsigned voff = n * 4u;

    float rxv[2], ryv[2], rzv[2], t0v[2], t1v[2], t2v[2];
#pragma unroll
    for (int v = 0; v < 2; ++v) {
        const float* m = mats + v * 12;
        rxv[v] = fmaf(m[0], fx, fmaf(m[1], fy, m[2]));
        ryv[v] = fmaf(m[3], fx, fmaf(m[4], fy, m[5]));
        rzv[v] = fmaf(m[6], fx, fmaf(m[7], fy, m[8]));
        t0v[v] = m[9]; t1v[v] = m[10]; t2v[v] = m[11];
    }

    // ---- reference window from depth plane 0 ----
    const float dep0 = *(const float*)((const char*)dvals + voff);
    int x0r[2], y0r[2];
    unsigned co[2][4];
#pragma unroll
    for (int v = 0; v < 2; ++v) {
        float pxn = fmaf(rxv[v], dep0, t0v[v]);
        float pyn = fmaf(ryv[v], dep0, t1v[v]);
        float z   = fmaf(rzv[v], dep0, t2v[v]);
        z = (fabsf(z) < 1e-6f) ? 1e-6f : z;
        float px = pxn / z, py = pyn / z;   // IEEE div
        int x0 = (int)floorf(px), y0 = (int)floorf(py);
        x0r[v] = x0; y0r[v] = y0;
        int cx0 = min(max(x0, 0), NW - 1);
        int cx1 = min(max(x0 + 1, 0), NW - 1);
        int cy0 = min(max(y0, 0), NH - 1);
        int cy1 = min(max(y0 + 1, 0), NH - 1);
        co[v][0] = (unsigned)(cy0 * NW + cx0) * 4u;
        co[v][1] = (unsigned)(cy0 * NW + cx1) * 4u;
        co[v][2] = (unsigned)(cy1 * NW + cx0) * 4u;
        co[v][3] = (unsigned)(cy1 * NW + cx1) * 4u;
    }

    // ---- stats: stream 16 channels into 45 quad-form coefficients ----
    float G1[10], G2[10], Cm[16], R1[4], R2[4];
    float r2 = 0.f;
#pragma unroll
    for (int k = 0; k < 10; ++k) { G1[k] = 0.f; G2[k] = 0.f; }
#pragma unroll
    for (int k = 0; k < 16; ++k) Cm[k] = 0.f;
#pragma unroll
    for (int k = 0; k < 4; ++k) { R1[k] = 0.f; R2[k] = 0.f; }

    const char* f1b = (const char*)(feats + (size_t)1 * NC * HW);
    const char* f2b = (const char*)(feats + (size_t)2 * NC * HW);
#pragma unroll
    for (int c = 0; c < NC; ++c) {
        const char* frc = (const char*)feats + (size_t)c * HW * 4;
        const char* f1c = f1b + (size_t)c * HW * 4;
        const char* f2c = f2b + (size_t)c * HW * 4;
        float r = *(const float*)(frc + voff);
        float g1[4], g2[4];
#pragma unroll
        for (int i = 0; i < 4; ++i) {
            g1[i] = *(const float*)(f1c + co[0][i]);
            g2[i] = *(const float*)(f2c + co[1][i]);
        }
        float w = wreg[c];
        float wr = w * r;
        r2 = fmaf(wr, r, r2);
        float wg1[4], wg2[4];
#pragma unroll
        for (int i = 0; i < 4; ++i) { wg1[i] = w * g1[i]; wg2[i] = w * g2[i]; }
#pragma unroll
        for (int i = 0; i < 4; ++i) {
            R1[i] = fmaf(wr, g1[i], R1[i]);
            R2[i] = fmaf(wr, g2[i], R2[i]);
        }
#pragma unroll
        for (int i = 0; i < 4; ++i)
#pragma unroll
            for (int j = i; j < 4; ++j) {
                G1[SYM(i, j)] = fmaf(wg1[i], g1[j], G1[SYM(i, j)]);
                G2[SYM(i, j)] = fmaf(wg2[i], g2[j], G2[SYM(i, j)]);
            }
#pragma unroll
        for (int i = 0; i < 4; ++i)
#pragma unroll
            for (int j = 0; j < 4; ++j)
                Cm[i * 4 + j] = fmaf(wg1[i], g2[j], Cm[i * 4 + j]);
    }
#pragma unroll
    for (int i = 0; i < 4; ++i)
#pragma unroll
        for (int j = i + 1; j < 4; ++j) {
            G1[SYM(i, j)] += G1[SYM(i, j)];
            G2[SYM(i, j)] += G2[SYM(i, j)];
        }

    // ---- 32 depth evals: divs batched 4-wide, zero loads on fast path ----
    float c[ND];
    float mx = -INFINITY;
#pragma unroll
    for (int ck = 0; ck < ND / 4; ++ck) {
        float pxs[2][4], pys[2][4];
#pragma unroll
        for (int dd = 0; dd < 4; ++dd) {
            const float depth = *(const float*)((const char*)dvals +
                                 (size_t)(ck * 4 + dd) * HW * 4 + voff);
#pragma unroll
            for (int v = 0; v < 2; ++v) {
                float pxn = fmaf(rxv[v], depth, t0v[v]);
                float pyn = fmaf(ryv[v], depth, t1v[v]);
                float z   = fmaf(rzv[v], depth, t2v[v]);
                z = (fabsf(z) < 1e-6f) ? 1e-6f : z;
                pxs[v][dd] = pxn / z;
                pys[v][dd] = pyn / z;
            }
        }
#pragma unroll
        for (int dd = 0; dd < 4; ++dd) {
            float al[2][4];
            int ax0[2], ay0[2];
            bool fast = true;
#pragma unroll
            for (int v = 0; v < 2; ++v) {
                float px = pxs[v][dd], py = pys[v][dd];
                float x0f = floorf(px), y0f = floorf(py);
                float wx = px - x0f, wy = py - y0f;
                int x0 = (int)x0f, y0 = (int)y0f;
                ax0[v] = x0; ay0[v] = y0;
                fast = fast && (x0 == x0r[v]) && (y0 == y0r[v]);
                bool vx0 = (x0 >= 0) && (x0 < NW);
                bool vx1 = (x0 + 1 >= 0) && (x0 + 1 < NW);
                bool vy0 = (y0 >= 0) && (y0 < NH);
                bool vy1 = (y0 + 1 >= 0) && (y0 + 1 < NH);
                al[v][0] = (1.f - wx) * (1.f - wy) * ((vx0 && vy0) ? 1.f : 0.f);
                al[v][1] = wx * (1.f - wy) * ((vx1 && vy0) ? 1.f : 0.f);
                al[v][2] = (1.f - wx) * wy * ((vx0 && vy1) ? 1.f : 0.f);
                al[v][3] = wx * wy * ((vx1 && vy1) ? 1.f : 0.f);
            }

            float cst;
            if (fast) {
                float q1 = 0.f, q2 = 0.f;
#pragma unroll
                for (int i = 0; i < 4; ++i)
#pragma unroll
                    for (int j = i; j < 4; ++j) {
                        q1 = fmaf(G1[SYM(i, j)], al[0][i] * al[0][j], q1);
                        q2 = fmaf(G2[SYM(i, j)], al[1][i] * al[1][j], q2);
                    }
                float qc = 0.f;
#pragma unroll
                for (int i = 0; i < 4; ++i)
#pragma unroll
                    for (int j = 0; j < 4; ++j)
                        qc = fmaf(Cm[i * 4 + j], al[0][i] * al[1][j], qc);
                float lr = 0.f;
#pragma unroll
                for (int i = 0; i < 4; ++i) {
                    lr = fmaf(R1[i], al[0][i], lr);
                    lr = fmaf(R2[i], al[1][i], lr);
                }
                cst = (2.f / 9.f) * (r2 + q1 + q2 - lr - qc);
            } else {
                // slow path: exact direct regather for deviant lanes only
                unsigned so[2][4];
#pragma unroll
                for (int v = 0; v < 2; ++v) {
                    int cx0 = min(max(ax0[v], 0), NW - 1);
                    int cx1 = min(max(ax0[v] + 1, 0), NW - 1);
                    int cy0 = min(max(ay0[v], 0), NH - 1);
                    int cy1 = min(max(ay0[v] + 1, 0), NH - 1);
                    so[v][0] = (unsigned)(cy0 * NW + cx0) * 4u;
                    so[v][1] = (unsigned)(cy0 * NW + cx1) * 4u;
                    so[v][2] = (unsigned)(cy1 * NW + cx0) * 4u;
                    so[v][3] = (unsigned)(cy1 * NW + cx1) * 4u;
                }
                float acc = 0.f;
#pragma unroll
                for (int cc = 0; cc < NC; ++cc) {
                    const char* frc = (const char*)feats + (size_t)cc * HW * 4;
                    const char* f1c = f1b + (size_t)cc * HW * 4;
                    const char* f2c = f2b + (size_t)cc * HW * 4;
                    float r = *(const float*)(frc + voff);
                    float s1 = 0.f, s2 = 0.f;
#pragma unroll
                    for (int i = 0; i < 4; ++i) {
                        s1 = fmaf(*(const float*)(f1c + so[0][i]), al[0][i], s1);
                        s2 = fmaf(*(const float*)(f2c + so[1][i]), al[1][i], s2);
                    }
                    float e = r * r + s1 * s1 + s2 * s2
                            - r * s1 - r * s2 - s1 * s2;
                    acc = fmaf(wreg[cc], e, acc);
                }
                cst = (2.f / 9.f) * acc;
            }
            c[ck * 4 + dd] = cst;
            mx = fmaxf(mx, cst);
        }
    }

    // ---- softmax + depth regression + confidence, all in registers ----
    float ssum = 0.f;
#pragma unroll
    for (int d = 0; d < ND; ++d) {
        float e = expf(c[d] - mx);
        c[d] = e;
        ssum += e;
    }
    float inv = 1.f / ssum;
    float* prob = out + 2 * HW;
    float depth_acc = 0.f, didx_acc = 0.f;
#pragma unroll
    for (int d = 0; d < ND; ++d) {
        float pv = c[d] * inv;
        c[d] = pv;
        *(float*)((char*)prob + (size_t)d * HW * 4 + voff) = pv;
        float dv = *(const float*)((const char*)dvals + (size_t)d * HW * 4 + voff);
        depth_acc = fmaf(pv, dv, depth_acc);
        didx_acc = fmaf(pv, (float)d, didx_acc);
    }
    int di = (int)didx_acc;            // trunc toward zero == astype(int32)
    di = min(max(di, 0), ND - 1);
    float pdi = 0.f, pdi1 = 0.f;
#pragma unroll
    for (int d = 0; d < ND; ++d) {
        pdi = (d == di) ? c[d] : pdi;
        pdi1 = (d == di + 1) ? c[d] : pdi1;
    }
    out[n] = depth_acc;
    out[HW + n] = pdi + pdi1;
}

extern "C" void kernel_launch(void* const* d_in, const int* in_sizes, int n_in,
                              void* d_out, int out_size, void* d_ws, size_t ws_size,
                              hipStream_t stream) {
    const float* feats = (const float*)d_in[0];
    const float* pm    = (const float*)d_in[1];
    const float* dvals = (const float*)d_in[2];
    const float* wreg  = (const float*)d_in[3];
    float* out = (float*)d_out;
    float* mats = (float*)d_ws;                  // 24 floats

    proj_setup_kernel<<<1, 64, 0, stream>>>(pm, mats);
    fused_kernel<<<HW / 64, 64, 0, stream>>>(feats, dvals, wreg, mats, out);
}

// Round 12
// 38.389 us; speedup vs baseline: 1.4630x; 1.4630x over previous
//
#include <hip/hip_runtime.h>
#include <math.h>

namespace {
constexpr int NV = 3;    // views
constexpr int NC = 16;   // channels
constexpr int ND = 32;   // depths
constexpr int NH = 256;
constexpr int NW = 320;
constexpr int HW = NH * NW;       // 81920
constexpr size_t COEF_OFF = 128;
constexpr size_t COEF_BYTES = (size_t)45 * HW * sizeof(float);  // 14.7 MB
#define SYM(i, j) ((i) * 4 + (j) - (i) * ((i) + 1) / 2)
}

// ---------------------------------------------------------------------------
// Setup: proj_v = P_v @ inv(P_0); store rot(9)+trans(3) per src view.
// ---------------------------------------------------------------------------
__global__ void proj_setup_kernel(const float* __restrict__ pm,
                                  float* __restrict__ mats) {
    if (threadIdx.x != 0 || blockIdx.x != 0) return;
    float P[NV][4][4];
    for (int v = 0; v < NV; ++v) {
        const float* E = pm + v * 2 * 16;
        const float* K = pm + v * 2 * 16 + 16;
        for (int i = 0; i < 4; ++i)
            for (int j = 0; j < 4; ++j)
                P[v][i][j] = E[i * 4 + j];
        for (int i = 0; i < 3; ++i)
            for (int j = 0; j < 4; ++j) {
                float acc = 0.f;
                for (int k = 0; k < 3; ++k) acc += K[i * 4 + k] * E[k * 4 + j];
                P[v][i][j] = acc;
            }
    }
    float A[4][8];
    for (int i = 0; i < 4; ++i)
        for (int j = 0; j < 4; ++j) {
            A[i][j] = P[0][i][j];
            A[i][j + 4] = (i == j) ? 1.f : 0.f;
        }
    for (int col = 0; col < 4; ++col) {
        int piv = col;
        float best = fabsf(A[col][col]);
        for (int r = col + 1; r < 4; ++r) {
            float av = fabsf(A[r][col]);
            if (av > best) { best = av; piv = r; }
        }
        if (piv != col)
            for (int j = 0; j < 8; ++j) {
                float t = A[col][j]; A[col][j] = A[piv][j]; A[piv][j] = t;
            }
        float inv = 1.f / A[col][col];
        for (int j = 0; j < 8; ++j) A[col][j] *= inv;
        for (int r = 0; r < 4; ++r) {
            if (r == col) continue;
            float f = A[r][col];
            if (f != 0.f)
                for (int j = 0; j < 8; ++j) A[r][j] -= f * A[col][j];
        }
    }
    float Inv[4][4];
    for (int i = 0; i < 4; ++i)
        for (int j = 0; j < 4; ++j) Inv[i][j] = A[i][j + 4];

    for (int v = 1; v < NV; ++v) {
        float M[4][4];
        for (int i = 0; i < 4; ++i)
            for (int j = 0; j < 4; ++j) {
                float acc = 0.f;
                for (int k = 0; k < 4; ++k) acc += P[v][i][k] * Inv[k][j];
                M[i][j] = acc;
            }
        float* o = mats + (v - 1) * 12;
        for (int i = 0; i < 3; ++i)
            for (int j = 0; j < 3; ++j) o[i * 3 + j] = M[i][j];
        for (int i = 0; i < 3; ++i) o[9 + i] = M[i][3];
    }
}

// ---------------------------------------------------------------------------
// Phase 1: per-pixel quad-form coefficients (depth-independent), SoA planes.
// 45 planes: 0 r2 | 1-4 R1 | 5-8 R2 | 9-18 G1 | 19-28 G2 | 29-44 Cm.
// ---------------------------------------------------------------------------
__global__ __launch_bounds__(64) void stats_kernel(
    const float* __restrict__ feats,   // [V][C][HW]
    const float* __restrict__ dvals,   // [D][HW]
    const float* __restrict__ wreg,    // [C]
    const float* __restrict__ mats,    // [2][12]
    float* __restrict__ coef)          // [45][HW]
{
    const unsigned n = blockIdx.x * 64u + threadIdx.x;
    const int y = (int)(n / NW);
    const int x = (int)(n - (unsigned)y * NW);
    const float fx = (float)x, fy = (float)y;
    const unsigned voff = n * 4u;

    float rxv[2], ryv[2], rzv[2], t0v[2], t1v[2], t2v[2];
#pragma unroll
    for (int v = 0; v < 2; ++v) {
        const float* m = mats + v * 12;
        rxv[v] = fmaf(m[0], fx, fmaf(m[1], fy, m[2]));
        ryv[v] = fmaf(m[3], fx, fmaf(m[4], fy, m[5]));
        rzv[v] = fmaf(m[6], fx, fmaf(m[7], fy, m[8]));
        t0v[v] = m[9]; t1v[v] = m[10]; t2v[v] = m[11];
    }

    const float dep0 = *(const float*)((const char*)dvals + voff); // plane 0
    unsigned co[2][4];
#pragma unroll
    for (int v = 0; v < 2; ++v) {
        float pxn = fmaf(rxv[v], dep0, t0v[v]);
        float pyn = fmaf(ryv[v], dep0, t1v[v]);
        float z   = fmaf(rzv[v], dep0, t2v[v]);
        z = (fabsf(z) < 1e-6f) ? 1e-6f : z;
        float px = pxn / z, py = pyn / z;    // IEEE div (matches eval)
        int x0 = (int)floorf(px), y0 = (int)floorf(py);
        int cx0 = min(max(x0, 0), NW - 1);
        int cx1 = min(max(x0 + 1, 0), NW - 1);
        int cy0 = min(max(y0, 0), NH - 1);
        int cy1 = min(max(y0 + 1, 0), NH - 1);
        co[v][0] = (unsigned)(cy0 * NW + cx0) * 4u;
        co[v][1] = (unsigned)(cy0 * NW + cx1) * 4u;
        co[v][2] = (unsigned)(cy1 * NW + cx0) * 4u;
        co[v][3] = (unsigned)(cy1 * NW + cx1) * 4u;
    }

    float G1[10], G2[10], Cm[16], R1[4], R2[4];
    float r2 = 0.f;
#pragma unroll
    for (int k = 0; k < 10; ++k) { G1[k] = 0.f; G2[k] = 0.f; }
#pragma unroll
    for (int k = 0; k < 16; ++k) Cm[k] = 0.f;
#pragma unroll
    for (int k = 0; k < 4; ++k) { R1[k] = 0.f; R2[k] = 0.f; }

    const char* f1b = (const char*)(feats + (size_t)1 * NC * HW);
    const char* f2b = (const char*)(feats + (size_t)2 * NC * HW);
#pragma unroll
    for (int c = 0; c < NC; ++c) {
        const char* frc = (const char*)feats + (size_t)c * HW * 4;
        const char* f1c = f1b + (size_t)c * HW * 4;
        const char* f2c = f2b + (size_t)c * HW * 4;
        float r = *(const float*)(frc + voff);
        float g1[4], g2[4];
#pragma unroll
        for (int i = 0; i < 4; ++i) {
            g1[i] = *(const float*)(f1c + co[0][i]);
            g2[i] = *(const float*)(f2c + co[1][i]);
        }
        float w = wreg[c];
        float wr = w * r;
        r2 = fmaf(wr, r, r2);
        float wg1[4], wg2[4];
#pragma unroll
        for (int i = 0; i < 4; ++i) { wg1[i] = w * g1[i]; wg2[i] = w * g2[i]; }
#pragma unroll
        for (int i = 0; i < 4; ++i) {
            R1[i] = fmaf(wr, g1[i], R1[i]);
            R2[i] = fmaf(wr, g2[i], R2[i]);
        }
#pragma unroll
        for (int i = 0; i < 4; ++i)
#pragma unroll
            for (int j = i; j < 4; ++j) {
                G1[SYM(i, j)] = fmaf(wg1[i], g1[j], G1[SYM(i, j)]);
                G2[SYM(i, j)] = fmaf(wg2[i], g2[j], G2[SYM(i, j)]);
            }
#pragma unroll
        for (int i = 0; i < 4; ++i)
#pragma unroll
            for (int j = 0; j < 4; ++j)
                Cm[i * 4 + j] = fmaf(wg1[i], g2[j], Cm[i * 4 + j]);
    }
#pragma unroll
    for (int i = 0; i < 4; ++i)
#pragma unroll
        for (int j = i + 1; j < 4; ++j) {
            G1[SYM(i, j)] += G1[SYM(i, j)];
            G2[SYM(i, j)] += G2[SYM(i, j)];
        }

    char* cb = (char*)coef;
    *(float*)(cb + (size_t)0 * HW * 4 + voff) = r2;
#pragma unroll
    for (int i = 0; i < 4; ++i) {
        *(float*)(cb + (size_t)(1 + i) * HW * 4 + voff) = R1[i];
        *(float*)(cb + (size_t)(5 + i) * HW * 4 + voff) = R2[i];
    }
#pragma unroll
    for (int k = 0; k < 10; ++k) {
        *(float*)(cb + (size_t)(9 + k) * HW * 4 + voff) = G1[k];
        *(float*)(cb + (size_t)(19 + k) * HW * 4 + voff) = G2[k];
    }
#pragma unroll
    for (int k = 0; k < 16; ++k)
        *(float*)(cb + (size_t)(29 + k) * HW * 4 + voff) = Cm[k];
}

// ---------------------------------------------------------------------------
// Phase 2 (R12): eval + softmax + depth/conf in ONE kernel, 4 lanes/pixel.
// Lanes 4k..4k+3 hold depths q*8..q*8+7 of pixel k (same wave) -> softmax /
// depth / didx / conf reductions are 2-step __shfl_xor(1,2) butterflies.
// Keeps eval's 5120-wave parallelism (R11's 1280-wave full fusion was
// latency-bound at 27% VALUBusy) while deleting the separate softmax kernel,
// the cost-plane round trip (21 MB), and a launch gap.
// ---------------------------------------------------------------------------
__global__ __launch_bounds__(256) void evalsm_kernel(
    const float* __restrict__ feats,
    const float* __restrict__ dvals,
    const float* __restrict__ wreg,
    const float* __restrict__ mats,
    const float* __restrict__ coef,    // [45][HW]
    float* __restrict__ out)           // depth[HW] | conf[HW] | prob[D][HW]
{
    const unsigned tid = blockIdx.x * 256u + threadIdx.x;
    const unsigned n = tid >> 2;           // pixel
    const int q = (int)(tid & 3u);         // depth quarter
    const int d0 = q * 8;
    const int y = (int)(n / NW);
    const int x = (int)(n - (unsigned)y * NW);
    const float fx = (float)x, fy = (float)y;
    const unsigned voff = n * 4u;

    float rxv[2], ryv[2], rzv[2], t0v[2], t1v[2], t2v[2];
#pragma unroll
    for (int v = 0; v < 2; ++v) {
        const float* m = mats + v * 12;
        rxv[v] = fmaf(m[0], fx, fmaf(m[1], fy, m[2]));
        ryv[v] = fmaf(m[3], fx, fmaf(m[4], fy, m[5]));
        rzv[v] = fmaf(m[6], fx, fmaf(m[7], fy, m[8]));
        t0v[v] = m[9]; t1v[v] = m[10]; t2v[v] = m[11];
    }

    // reference window from depth plane 0 (same expressions as stats_kernel)
    const float dep0 = *(const float*)((const char*)dvals + voff);
    int x0r[2], y0r[2];
#pragma unroll
    for (int v = 0; v < 2; ++v) {
        float pxn = fmaf(rxv[v], dep0, t0v[v]);
        float pyn = fmaf(ryv[v], dep0, t1v[v]);
        float z   = fmaf(rzv[v], dep0, t2v[v]);
        z = (fabsf(z) < 1e-6f) ? 1e-6f : z;
        float px = pxn / z, py = pyn / z;
        x0r[v] = (int)floorf(px);
        y0r[v] = (int)floorf(py);
    }

    // 45 coefficient loads (SGPR bases + shared voffset; 4-lane broadcast)
    const char* cb = (const char*)coef;
    float r2 = *(const float*)(cb + (size_t)0 * HW * 4 + voff);
    float R1[4], R2[4], G1[10], G2[10], Cm[16];
#pragma unroll
    for (int i = 0; i < 4; ++i) {
        R1[i] = *(const float*)(cb + (size_t)(1 + i) * HW * 4 + voff);
        R2[i] = *(const float*)(cb + (size_t)(5 + i) * HW * 4 + voff);
    }
#pragma unroll
    for (int k = 0; k < 10; ++k) {
        G1[k] = *(const float*)(cb + (size_t)(9 + k) * HW * 4 + voff);
        G2[k] = *(const float*)(cb + (size_t)(19 + k) * HW * 4 + voff);
    }
#pragma unroll
    for (int k = 0; k < 16; ++k)
        Cm[k] = *(const float*)(cb + (size_t)(29 + k) * HW * 4 + voff);

    const char* f1b = (const char*)(feats + (size_t)1 * NC * HW);
    const char* f2b = (const char*)(feats + (size_t)2 * NC * HW);

    // ---- 8 depth evals (divs batched 4-wide), costs into c[8] ----
    float c[8], dv[8];
    float mx = -INFINITY;
#pragma unroll
    for (int ck = 0; ck < 2; ++ck) {
        float pxs[2][4], pys[2][4];
#pragma unroll
        for (int dd = 0; dd < 4; ++dd) {
            const float depth = *(const float*)((const char*)dvals +
                                 (size_t)(d0 + ck * 4 + dd) * HW * 4 + voff);
            dv[ck * 4 + dd] = depth;
#pragma unroll
            for (int v = 0; v < 2; ++v) {
                float pxn = fmaf(rxv[v], depth, t0v[v]);
                float pyn = fmaf(ryv[v], depth, t1v[v]);
                float z   = fmaf(rzv[v], depth, t2v[v]);
                z = (fabsf(z) < 1e-6f) ? 1e-6f : z;
                pxs[v][dd] = pxn / z;
                pys[v][dd] = pyn / z;
            }
        }
#pragma unroll
        for (int dd = 0; dd < 4; ++dd) {
            float al[2][4];
            int ax0[2], ay0[2];
            bool fast = true;
#pragma unroll
            for (int v = 0; v < 2; ++v) {
                float px = pxs[v][dd], py = pys[v][dd];
                float x0f = floorf(px), y0f = floorf(py);
                float wx = px - x0f, wy = py - y0f;
                int x0 = (int)x0f, y0 = (int)y0f;
                ax0[v] = x0; ay0[v] = y0;
                fast = fast && (x0 == x0r[v]) && (y0 == y0r[v]);
                bool vx0 = (x0 >= 0) && (x0 < NW);
                bool vx1 = (x0 + 1 >= 0) && (x0 + 1 < NW);
                bool vy0 = (y0 >= 0) && (y0 < NH);
                bool vy1 = (y0 + 1 >= 0) && (y0 + 1 < NH);
                al[v][0] = (1.f - wx) * (1.f - wy) * ((vx0 && vy0) ? 1.f : 0.f);
                al[v][1] = wx * (1.f - wy) * ((vx1 && vy0) ? 1.f : 0.f);
                al[v][2] = (1.f - wx) * wy * ((vx0 && vy1) ? 1.f : 0.f);
                al[v][3] = wx * wy * ((vx1 && vy1) ? 1.f : 0.f);
            }

            float cst;
            if (fast) {
                float q1 = 0.f, q2 = 0.f;
#pragma unroll
                for (int i = 0; i < 4; ++i)
#pragma unroll
                    for (int j = i; j < 4; ++j) {
                        q1 = fmaf(G1[SYM(i, j)], al[0][i] * al[0][j], q1);
                        q2 = fmaf(G2[SYM(i, j)], al[1][i] * al[1][j], q2);
                    }
                float qc = 0.f;
#pragma unroll
                for (int i = 0; i < 4; ++i)
#pragma unroll
                    for (int j = 0; j < 4; ++j)
                        qc = fmaf(Cm[i * 4 + j], al[0][i] * al[1][j], qc);
                float lr = 0.f;
#pragma unroll
                for (int i = 0; i < 4; ++i) {
                    lr = fmaf(R1[i], al[0][i], lr);
                    lr = fmaf(R2[i], al[1][i], lr);
                }
                cst = (2.f / 9.f) * (r2 + q1 + q2 - lr - qc);
            } else {
                // slow path: exact direct regather for deviant lanes only
                unsigned so[2][4];
#pragma unroll
                for (int v = 0; v < 2; ++v) {
                    int cx0 = min(max(ax0[v], 0), NW - 1);
                    int cx1 = min(max(ax0[v] + 1, 0), NW - 1);
                    int cy0 = min(max(ay0[v], 0), NH - 1);
                    int cy1 = min(max(ay0[v] + 1, 0), NH - 1);
                    so[v][0] = (unsigned)(cy0 * NW + cx0) * 4u;
                    so[v][1] = (unsigned)(cy0 * NW + cx1) * 4u;
                    so[v][2] = (unsigned)(cy1 * NW + cx0) * 4u;
                    so[v][3] = (unsigned)(cy1 * NW + cx1) * 4u;
                }
                float acc = 0.f;
#pragma unroll
                for (int cc = 0; cc < NC; ++cc) {
                    const char* frc = (const char*)feats + (size_t)cc * HW * 4;
                    const char* f1c = f1b + (size_t)cc * HW * 4;
                    const char* f2c = f2b + (size_t)cc * HW * 4;
                    float r = *(const float*)(frc + voff);
                    float s1 = 0.f, s2 = 0.f;
#pragma unroll
                    for (int i = 0; i < 4; ++i) {
                        s1 = fmaf(*(const float*)(f1c + so[0][i]), al[0][i], s1);
                        s2 = fmaf(*(const float*)(f2c + so[1][i]), al[1][i], s2);
                    }
                    float e = r * r + s1 * s1 + s2 * s2
                            - r * s1 - r * s2 - s1 * s2;
                    acc = fmaf(wreg[cc], e, acc);
                }
                cst = (2.f / 9.f) * acc;
            }
            c[ck * 4 + dd] = cst;
            mx = fmaxf(mx, cst);
        }
    }

    // ---- cross-lane softmax over the 4-lane group ----
    mx = fmaxf(mx, __shfl_xor(mx, 1));
    mx = fmaxf(mx, __shfl_xor(mx, 2));
    float ssum = 0.f;
#pragma unroll
    for (int i = 0; i < 8; ++i) {
        float e = expf(c[i] - mx);
        c[i] = e;
        ssum += e;
    }
    ssum += __shfl_xor(ssum, 1);
    ssum += __shfl_xor(ssum, 2);
    float inv = 1.f / ssum;

    float* prob = out + 2 * HW;
    float depth_acc = 0.f, didx_acc = 0.f;
#pragma unroll
    for (int i = 0; i < 8; ++i) {
        float pv = c[i] * inv;
        c[i] = pv;
        *(float*)((char*)prob + (size_t)(d0 + i) * HW * 4 + voff) = pv;
        depth_acc = fmaf(pv, dv[i], depth_acc);
        didx_acc = fmaf(pv, (float)(d0 + i), didx_acc);
    }
    depth_acc += __shfl_xor(depth_acc, 1);
    depth_acc += __shfl_xor(depth_acc, 2);
    didx_acc += __shfl_xor(didx_acc, 1);
    didx_acc += __shfl_xor(didx_acc, 2);

    int di = (int)didx_acc;            // trunc toward zero == astype(int32)
    di = min(max(di, 0), ND - 1);
    float pdi = 0.f, pdi1 = 0.f;
#pragma unroll
    for (int i = 0; i < 8; ++i) {
        pdi  = (d0 + i == di)     ? c[i] : pdi;
        pdi1 = (d0 + i == di + 1) ? c[i] : pdi1;
    }
    pdi  += __shfl_xor(pdi, 1);
    pdi  += __shfl_xor(pdi, 2);
    pdi1 += __shfl_xor(pdi1, 1);
    pdi1 += __shfl_xor(pdi1, 2);

    if (q == 0) {
        out[n] = depth_acc;
        out[HW + n] = pdi + pdi1;
    }
}

// ---------------------------------------------------------------------------
// Fallback (R11 fused kernel) if ws can't hold the coefficient planes.
// ---------------------------------------------------------------------------
__global__ __launch_bounds__(64) void fused_kernel(
    const float* __restrict__ feats,
    const float* __restrict__ dvals,
    const float* __restrict__ wreg,
    const float* __restrict__ mats,
    float* __restrict__ out)
{
    const unsigned n = blockIdx.x * 64u + threadIdx.x;
    const int y = (int)(n / NW);
    const int x = (int)(n - (unsigned)y * NW);
    const float fx = (float)x, fy = (float)y;
    const unsigned voff = n * 4u;

    float rxv[2], ryv[2], rzv[2], t0v[2], t1v[2], t2v[2];
#pragma unroll
    for (int v = 0; v < 2; ++v) {
        const float* m = mats + v * 12;
        rxv[v] = fmaf(m[0], fx, fmaf(m[1], fy, m[2]));
        ryv[v] = fmaf(m[3], fx, fmaf(m[4], fy, m[5]));
        rzv[v] = fmaf(m[6], fx, fmaf(m[7], fy, m[8]));
        t0v[v] = m[9]; t1v[v] = m[10]; t2v[v] = m[11];
    }

    const float dep0 = *(const float*)((const char*)dvals + voff);
    int x0r[2], y0r[2];
    unsigned co[2][4];
#pragma unroll
    for (int v = 0; v < 2; ++v) {
        float pxn = fmaf(rxv[v], dep0, t0v[v]);
        float pyn = fmaf(ryv[v], dep0, t1v[v]);
        float z   = fmaf(rzv[v], dep0, t2v[v]);
        z = (fabsf(z) < 1e-6f) ? 1e-6f : z;
        float px = pxn / z, py = pyn / z;
        int x0 = (int)floorf(px), y0 = (int)floorf(py);
        x0r[v] = x0; y0r[v] = y0;
        int cx0 = min(max(x0, 0), NW - 1);
        int cx1 = min(max(x0 + 1, 0), NW - 1);
        int cy0 = min(max(y0, 0), NH - 1);
        int cy1 = min(max(y0 + 1, 0), NH - 1);
        co[v][0] = (unsigned)(cy0 * NW + cx0) * 4u;
        co[v][1] = (unsigned)(cy0 * NW + cx1) * 4u;
        co[v][2] = (unsigned)(cy1 * NW + cx0) * 4u;
        co[v][3] = (unsigned)(cy1 * NW + cx1) * 4u;
    }

    float G1[10], G2[10], Cm[16], R1[4], R2[4];
    float r2 = 0.f;
#pragma unroll
    for (int k = 0; k < 10; ++k) { G1[k] = 0.f; G2[k] = 0.f; }
#pragma unroll
    for (int k = 0; k < 16; ++k) Cm[k] = 0.f;
#pragma unroll
    for (int k = 0; k < 4; ++k) { R1[k] = 0.f; R2[k] = 0.f; }

    const char* f1b = (const char*)(feats + (size_t)1 * NC * HW);
    const char* f2b = (const char*)(feats + (size_t)2 * NC * HW);
#pragma unroll
    for (int c = 0; c < NC; ++c) {
        const char* frc = (const char*)feats + (size_t)c * HW * 4;
        const char* f1c = f1b + (size_t)c * HW * 4;
        const char* f2c = f2b + (size_t)c * HW * 4;
        float r = *(const float*)(frc + voff);
        float g1[4], g2[4];
#pragma unroll
        for (int i = 0; i < 4; ++i) {
            g1[i] = *(const float*)(f1c + co[0][i]);
            g2[i] = *(const float*)(f2c + co[1][i]);
        }
        float w = wreg[c];
        float wr = w * r;
        r2 = fmaf(wr, r, r2);
        float wg1[4], wg2[4];
#pragma unroll
        for (int i = 0; i < 4; ++i) { wg1[i] = w * g1[i]; wg2[i] = w * g2[i]; }
#pragma unroll
        for (int i = 0; i < 4; ++i) {
            R1[i] = fmaf(wr, g1[i], R1[i]);
            R2[i] = fmaf(wr, g2[i], R2[i]);
        }
#pragma unroll
        for (int i = 0; i < 4; ++i)
#pragma unroll
            for (int j = i; j < 4; ++j) {
                G1[SYM(i, j)] = fmaf(wg1[i], g1[j], G1[SYM(i, j)]);
                G2[SYM(i, j)] = fmaf(wg2[i], g2[j], G2[SYM(i, j)]);
            }
#pragma unroll
        for (int i = 0; i < 4; ++i)
#pragma unroll
            for (int j = 0; j < 4; ++j)
                Cm[i * 4 + j] = fmaf(wg1[i], g2[j], Cm[i * 4 + j]);
    }
#pragma unroll
    for (int i = 0; i < 4; ++i)
#pragma unroll
        for (int j = i + 1; j < 4; ++j) {
            G1[SYM(i, j)] += G1[SYM(i, j)];
            G2[SYM(i, j)] += G2[SYM(i, j)];
        }

    float c[ND];
    float mx = -INFINITY;
#pragma unroll
    for (int ck = 0; ck < ND / 4; ++ck) {
        float pxs[2][4], pys[2][4];
#pragma unroll
        for (int dd = 0; dd < 4; ++dd) {
            const float depth = *(const float*)((const char*)dvals +
                                 (size_t)(ck * 4 + dd) * HW * 4 + voff);
#pragma unroll
            for (int v = 0; v < 2; ++v) {
                float pxn = fmaf(rxv[v], depth, t0v[v]);
                float pyn = fmaf(ryv[v], depth, t1v[v]);
                float z   = fmaf(rzv[v], depth, t2v[v]);
                z = (fabsf(z) < 1e-6f) ? 1e-6f : z;
                pxs[v][dd] = pxn / z;
                pys[v][dd] = pyn / z;
            }
        }
#pragma unroll
        for (int dd = 0; dd < 4; ++dd) {
            float al[2][4];
            int ax0[2], ay0[2];
            bool fast = true;
#pragma unroll
            for (int v = 0; v < 2; ++v) {
                float px = pxs[v][dd], py = pys[v][dd];
                float x0f = floorf(px), y0f = floorf(py);
                float wx = px - x0f, wy = py - y0f;
                int x0 = (int)x0f, y0 = (int)y0f;
                ax0[v] = x0; ay0[v] = y0;
                fast = fast && (x0 == x0r[v]) && (y0 == y0r[v]);
                bool vx0 = (x0 >= 0) && (x0 < NW);
                bool vx1 = (x0 + 1 >= 0) && (x0 + 1 < NW);
                bool vy0 = (y0 >= 0) && (y0 < NH);
                bool vy1 = (y0 + 1 >= 0) && (y0 + 1 < NH);
                al[v][0] = (1.f - wx) * (1.f - wy) * ((vx0 && vy0) ? 1.f : 0.f);
                al[v][1] = wx * (1.f - wy) * ((vx1 && vy0) ? 1.f : 0.f);
                al[v][2] = (1.f - wx) * wy * ((vx0 && vy1) ? 1.f : 0.f);
                al[v][3] = wx * wy * ((vx1 && vy1) ? 1.f : 0.f);
            }

            float cst;
            if (fast) {
                float q1 = 0.f, q2 = 0.f;
#pragma unroll
                for (int i = 0; i < 4; ++i)
#pragma unroll
                    for (int j = i; j < 4; ++j) {
                        q1 = fmaf(G1[SYM(i, j)], al[0][i] * al[0][j], q1);
                        q2 = fmaf(G2[SYM(i, j)], al[1][i] * al[1][j], q2);
                    }
                float qc = 0.f;
#pragma unroll
                for (int i = 0; i < 4; ++i)
#pragma unroll
                    for (int j = 0; j < 4; ++j)
                        qc = fmaf(Cm[i * 4 + j], al[0][i] * al[1][j], qc);
                float lr = 0.f;
#pragma unroll
                for (int i = 0; i < 4; ++i) {
                    lr = fmaf(R1[i], al[0][i], lr);
                    lr = fmaf(R2[i], al[1][i], lr);
                }
                cst = (2.f / 9.f) * (r2 + q1 + q2 - lr - qc);
            } else {
                unsigned so[2][4];
#pragma unroll
                for (int v = 0; v < 2; ++v) {
                    int cx0 = min(max(ax0[v], 0), NW - 1);
                    int cx1 = min(max(ax0[v] + 1, 0), NW - 1);
                    int cy0 = min(max(ay0[v], 0), NH - 1);
                    int cy1 = min(max(ay0[v] + 1, 0), NH - 1);
                    so[v][0] = (unsigned)(cy0 * NW + cx0) * 4u;
                    so[v][1] = (unsigned)(cy0 * NW + cx1) * 4u;
                    so[v][2] = (unsigned)(cy1 * NW + cx0) * 4u;
                    so[v][3] = (unsigned)(cy1 * NW + cx1) * 4u;
                }
                float acc = 0.f;
#pragma unroll
                for (int cc = 0; cc < NC; ++cc) {
                    const char* frc = (const char*)feats + (size_t)cc * HW * 4;
                    const char* f1c = f1b + (size_t)cc * HW * 4;
                    const char* f2c = f2b + (size_t)cc * HW * 4;
                    float r = *(const float*)(frc + voff);
                    float s1 = 0.f, s2 = 0.f;
#pragma unroll
                    for (int i = 0; i < 4; ++i) {
                        s1 = fmaf(*(const float*)(f1c + so[0][i]), al[0][i], s1);
                        s2 = fmaf(*(const float*)(f2c + so[1][i]), al[1][i], s2);
                    }
                    float e = r * r + s1 * s1 + s2 * s2
                            - r * s1 - r * s2 - s1 * s2;
                    acc = fmaf(wreg[cc], e, acc);
                }
                cst = (2.f / 9.f) * acc;
            }
            c[ck * 4 + dd] = cst;
            mx = fmaxf(mx, cst);
        }
    }

    float ssum = 0.f;
#pragma unroll
    for (int d = 0; d < ND; ++d) {
        float e = expf(c[d] - mx);
        c[d] = e;
        ssum += e;
    }
    float inv = 1.f / ssum;
    float* prob = out + 2 * HW;
    float depth_acc = 0.f, didx_acc = 0.f;
#pragma unroll
    for (int d = 0; d < ND; ++d) {
        float pv = c[d] * inv;
        c[d] = pv;
        *(float*)((char*)prob + (size_t)d * HW * 4 + voff) = pv;
        float dvv = *(const float*)((const char*)dvals + (size_t)d * HW * 4 + voff);
        depth_acc = fmaf(pv, dvv, depth_acc);
        didx_acc = fmaf(pv, (float)d, didx_acc);
    }
    int di = (int)didx_acc;
    di = min(max(di, 0), ND - 1);
    float pdi = 0.f, pdi1 = 0.f;
#pragma unroll
    for (int d = 0; d < ND; ++d) {
        pdi = (d == di) ? c[d] : pdi;
        pdi1 = (d == di + 1) ? c[d] : pdi1;
    }
    out[n] = depth_acc;
    out[HW + n] = pdi + pdi1;
}

extern "C" void kernel_launch(void* const* d_in, const int* in_sizes, int n_in,
                              void* d_out, int out_size, void* d_ws, size_t ws_size,
                              hipStream_t stream) {
    const float* feats = (const float*)d_in[0];
    const float* pm    = (const float*)d_in[1];
    const float* dvals = (const float*)d_in[2];
    const float* wreg  = (const float*)d_in[3];
    float* out = (float*)d_out;
    float* mats = (float*)d_ws;                  // 24 floats

    proj_setup_kernel<<<1, 64, 0, stream>>>(pm, mats);

    if (ws_size >= COEF_OFF + COEF_BYTES) {
        float* coef = (float*)((char*)d_ws + COEF_OFF);
        stats_kernel<<<HW / 64, 64, 0, stream>>>(feats, dvals, wreg, mats,
                                                 coef);
        evalsm_kernel<<<HW * 4 / 256, 256, 0, stream>>>(feats, dvals, wreg,
                                                        mats, coef, out);
    } else {
        fused_kernel<<<HW / 64, 64, 0, stream>>>(feats, dvals, wreg, mats,
                                                 out);
    }
}

// Round 13
// 34.744 us; speedup vs baseline: 1.6164x; 1.1049x over previous
//
#include <hip/hip_runtime.h>
#include <math.h>

namespace {
constexpr int NV = 3;    // views
constexpr int NC = 16;   // channels
constexpr int ND = 32;   // depths
constexpr int NH = 256;
constexpr int NW = 320;
constexpr int HW = NH * NW;       // 81920
constexpr size_t COEF_OFF = 128;
constexpr size_t COEF_BYTES = (size_t)34 * HW * sizeof(float);  // 11.1 MB
#define SYM(i, j) ((i) * 4 + (j) - (i) * ((i) + 1) / 2)
}

// rcp + 1 Newton step; used IDENTICALLY by stats and eval so window anchors
// match bitwise. Any floor-flip vs the reference's IEEE div is caught by the
// fast-path window check (-> exact slow path); bilinear interp is continuous
// across window boundaries so 1-ulp px jitter is ~1-ulp output jitter.
__device__ __forceinline__ float frcp(float z) {
    float r = __builtin_amdgcn_rcpf(z);
    return r * fmaf(-z, r, 2.0f);
}

// ---------------------------------------------------------------------------
// Setup: proj_v = P_v @ inv(P_0); store rot(9)+trans(3) per src view.
// ---------------------------------------------------------------------------
__global__ void proj_setup_kernel(const float* __restrict__ pm,
                                  float* __restrict__ mats) {
    if (threadIdx.x != 0 || blockIdx.x != 0) return;
    float P[NV][4][4];
    for (int v = 0; v < NV; ++v) {
        const float* E = pm + v * 2 * 16;
        const float* K = pm + v * 2 * 16 + 16;
        for (int i = 0; i < 4; ++i)
            for (int j = 0; j < 4; ++j)
                P[v][i][j] = E[i * 4 + j];
        for (int i = 0; i < 3; ++i)
            for (int j = 0; j < 4; ++j) {
                float acc = 0.f;
                for (int k = 0; k < 3; ++k) acc += K[i * 4 + k] * E[k * 4 + j];
                P[v][i][j] = acc;
            }
    }
    float A[4][8];
    for (int i = 0; i < 4; ++i)
        for (int j = 0; j < 4; ++j) {
            A[i][j] = P[0][i][j];
            A[i][j + 4] = (i == j) ? 1.f : 0.f;
        }
    for (int col = 0; col < 4; ++col) {
        int piv = col;
        float best = fabsf(A[col][col]);
        for (int r = col + 1; r < 4; ++r) {
            float av = fabsf(A[r][col]);
            if (av > best) { best = av; piv = r; }
        }
        if (piv != col)
            for (int j = 0; j < 8; ++j) {
                float t = A[col][j]; A[col][j] = A[piv][j]; A[piv][j] = t;
            }
        float inv = 1.f / A[col][col];
        for (int j = 0; j < 8; ++j) A[col][j] *= inv;
        for (int r = 0; r < 4; ++r) {
            if (r == col) continue;
            float f = A[r][col];
            if (f != 0.f)
                for (int j = 0; j < 8; ++j) A[r][j] -= f * A[col][j];
        }
    }
    float Inv[4][4];
    for (int i = 0; i < 4; ++i)
        for (int j = 0; j < 4; ++j) Inv[i][j] = A[i][j + 4];

    for (int v = 1; v < NV; ++v) {
        float M[4][4];
        for (int i = 0; i < 4; ++i)
            for (int j = 0; j < 4; ++j) {
                float acc = 0.f;
                for (int k = 0; k < 4; ++k) acc += P[v][i][k] * Inv[k][j];
                M[i][j] = acc;
            }
        float* o = mats + (v - 1) * 12;
        for (int i = 0; i < 3; ++i)
            for (int j = 0; j < 3; ++j) o[i * 3 + j] = M[i][j];
        for (int i = 0; i < 3; ++i) o[9 + i] = M[i][3];
    }
}

// ---------------------------------------------------------------------------
// Phase 1 (R13): per-pixel POLYNOMIAL coefficients, 4 lanes/pixel (4 channels
// each, butterfly-allreduce). Corner validity masks (fixed for the pinned d0
// window) are folded into the gathered values, so the fast path uses pure
// bilinear weights. The 45 quad-form sums are converted once per pixel into:
//   planes 0-8 : A[p*3+q]   biquadratic in (wx0,wy0), incl. r2 and -R1'a
//   planes 9-17: B[p*3+q]   biquadratic in (wx1,wy1), incl. -R2'b
//   planes 18-33: X[p*8+q*4+r*2+s]  multilinear in (wx0,wy0,wx1,wy1) = -a'Cb
// cost_pre(d) = A(wx0,wy0) + B(wx1,wy1) + X(...); cost = (2/9)*cost_pre.
// ---------------------------------------------------------------------------
__global__ __launch_bounds__(256) void stats4_kernel(
    const float* __restrict__ feats,   // [V][C][HW]
    const float* __restrict__ dvals,   // [D][HW]
    const float* __restrict__ wreg,    // [C]
    const float* __restrict__ mats,    // [2][12]
    float* __restrict__ coef)          // [34][HW]
{
    const unsigned tid = blockIdx.x * 256u + threadIdx.x;
    const unsigned n = tid >> 2;       // pixel
    const int q = (int)(tid & 3u);     // channel quarter / store quarter
    const int y = (int)(n / NW);
    const int x = (int)(n - (unsigned)y * NW);
    const float fx = (float)x, fy = (float)y;
    const unsigned voff = n * 4u;

    float rxv[2], ryv[2], rzv[2], t0v[2], t1v[2], t2v[2];
#pragma unroll
    for (int v = 0; v < 2; ++v) {
        const float* m = mats + v * 12;
        rxv[v] = fmaf(m[0], fx, fmaf(m[1], fy, m[2]));
        ryv[v] = fmaf(m[3], fx, fmaf(m[4], fy, m[5]));
        rzv[v] = fmaf(m[6], fx, fmaf(m[7], fy, m[8]));
        t0v[v] = m[9]; t1v[v] = m[10]; t2v[v] = m[11];
    }

    const float dep0 = *(const float*)((const char*)dvals + voff); // plane 0
    unsigned co[2][4];
    float mk[2][4];                    // corner validity for the d0 window
#pragma unroll
    for (int v = 0; v < 2; ++v) {
        float pxn = fmaf(rxv[v], dep0, t0v[v]);
        float pyn = fmaf(ryv[v], dep0, t1v[v]);
        float z   = fmaf(rzv[v], dep0, t2v[v]);
        z = (fabsf(z) < 1e-6f) ? 1e-6f : z;
        float ri = frcp(z);
        float px = pxn * ri, py = pyn * ri;
        int x0 = (int)floorf(px), y0 = (int)floorf(py);
        bool vx0 = (x0 >= 0) && (x0 < NW);
        bool vx1 = (x0 + 1 >= 0) && (x0 + 1 < NW);
        bool vy0 = (y0 >= 0) && (y0 < NH);
        bool vy1 = (y0 + 1 >= 0) && (y0 + 1 < NH);
        mk[v][0] = (vx0 && vy0) ? 1.f : 0.f;
        mk[v][1] = (vx1 && vy0) ? 1.f : 0.f;
        mk[v][2] = (vx0 && vy1) ? 1.f : 0.f;
        mk[v][3] = (vx1 && vy1) ? 1.f : 0.f;
        int cx0 = min(max(x0, 0), NW - 1);
        int cx1 = min(max(x0 + 1, 0), NW - 1);
        int cy0 = min(max(y0, 0), NH - 1);
        int cy1 = min(max(y0 + 1, 0), NH - 1);
        co[v][0] = (unsigned)(cy0 * NW + cx0) * 4u;
        co[v][1] = (unsigned)(cy0 * NW + cx1) * 4u;
        co[v][2] = (unsigned)(cy1 * NW + cx0) * 4u;
        co[v][3] = (unsigned)(cy1 * NW + cx1) * 4u;
    }

    // ---- accumulate quad-form sums over THIS LANE's 4 channels ----
    float G1[10], G2[10], Cm[16], R1[4], R2[4];
    float r2 = 0.f;
#pragma unroll
    for (int k = 0; k < 10; ++k) { G1[k] = 0.f; G2[k] = 0.f; }
#pragma unroll
    for (int k = 0; k < 16; ++k) Cm[k] = 0.f;
#pragma unroll
    for (int k = 0; k < 4; ++k) { R1[k] = 0.f; R2[k] = 0.f; }

    const char* fb = (const char*)feats;
    const char* f1b = fb + (size_t)1 * NC * HW * 4;
    const char* f2b = fb + (size_t)2 * NC * HW * 4;
#pragma unroll
    for (int c4 = 0; c4 < 4; ++c4) {
        const int c = q * 4 + c4;
        const char* frc = fb + (size_t)c * HW * 4;
        const char* f1c = f1b + (size_t)c * HW * 4;
        const char* f2c = f2b + (size_t)c * HW * 4;
        float r = *(const float*)(frc + voff);
        float g1[4], g2[4];
#pragma unroll
        for (int i = 0; i < 4; ++i) {
            g1[i] = *(const float*)(f1c + co[0][i]) * mk[0][i];  // mask folded
            g2[i] = *(const float*)(f2c + co[1][i]) * mk[1][i];
        }
        float w = wreg[c];
        float wr = w * r;
        r2 = fmaf(wr, r, r2);
        float wg1[4], wg2[4];
#pragma unroll
        for (int i = 0; i < 4; ++i) { wg1[i] = w * g1[i]; wg2[i] = w * g2[i]; }
#pragma unroll
        for (int i = 0; i < 4; ++i) {
            R1[i] = fmaf(wr, g1[i], R1[i]);
            R2[i] = fmaf(wr, g2[i], R2[i]);
        }
#pragma unroll
        for (int i = 0; i < 4; ++i)
#pragma unroll
            for (int j = i; j < 4; ++j) {            // pure SYM, no doubling
                G1[SYM(i, j)] = fmaf(wg1[i], g1[j], G1[SYM(i, j)]);
                G2[SYM(i, j)] = fmaf(wg2[i], g2[j], G2[SYM(i, j)]);
            }
#pragma unroll
        for (int i = 0; i < 4; ++i)
#pragma unroll
            for (int j = 0; j < 4; ++j)
                Cm[i * 4 + j] = fmaf(wg1[i], g2[j], Cm[i * 4 + j]);
    }

    // ---- butterfly allreduce across the 4-lane group (bitwise-identical
    //      on every lane: commutative pairings only) ----
#pragma unroll
    for (int k = 0; k < 10; ++k) {
        G1[k] += __shfl_xor(G1[k], 1); G1[k] += __shfl_xor(G1[k], 2);
        G2[k] += __shfl_xor(G2[k], 1); G2[k] += __shfl_xor(G2[k], 2);
    }
#pragma unroll
    for (int k = 0; k < 16; ++k) {
        Cm[k] += __shfl_xor(Cm[k], 1); Cm[k] += __shfl_xor(Cm[k], 2);
    }
#pragma unroll
    for (int k = 0; k < 4; ++k) {
        R1[k] += __shfl_xor(R1[k], 1); R1[k] += __shfl_xor(R1[k], 2);
        R2[k] += __shfl_xor(R2[k], 1); R2[k] += __shfl_xor(R2[k], 2);
    }
    r2 += __shfl_xor(r2, 1); r2 += __shfl_xor(r2, 2);

    // ---- basis change: quad-form -> polynomial coefficients ----
    // u0u0=(1,-2,1), u0u1=(0,1,-1), u1u1=(0,0,1) in {1,w,w^2};
    // u0=(1,-1), u1=(0,1) in {1,w}. Corner i: m=i&1 (x), k=i>>1 (y).
    static constexpr float U2[3][3] = {{1.f,-2.f,1.f},{0.f,1.f,-1.f},{0.f,0.f,1.f}};
    static constexpr float U1[2][2] = {{1.f,-1.f},{0.f,1.f}};

    float A[9], Bp[9], Xc[16];
#pragma unroll
    for (int k = 0; k < 9; ++k) { A[k] = 0.f; Bp[k] = 0.f; }
#pragma unroll
    for (int k = 0; k < 16; ++k) Xc[k] = 0.f;
    A[0] = r2;

#pragma unroll
    for (int i = 0; i < 4; ++i) {
#pragma unroll
        for (int j = 0; j < 4; ++j) {
            const int lo = i < j ? i : j, hi = i < j ? j : i;
            const float g1v = G1[SYM(lo, hi)];
            const float g2v = G2[SYM(lo, hi)];
            const int m = i & 1, kk = i >> 1, nn = j & 1, ll = j >> 1;
#pragma unroll
            for (int p = 0; p < 3; ++p) {
#pragma unroll
                for (int qq = 0; qq < 3; ++qq) {
                    const float cc = U2[m + nn][p] * U2[kk + ll][qq];
                    if (cc != 0.f) {
                        A[p * 3 + qq] += g1v * cc;
                        Bp[p * 3 + qq] += g2v * cc;
                    }
                }
            }
        }
    }
#pragma unroll
    for (int i = 0; i < 4; ++i) {
        const int m = i & 1, kk = i >> 1;
#pragma unroll
        for (int p = 0; p < 2; ++p)
#pragma unroll
            for (int qq = 0; qq < 2; ++qq) {
                const float cc = U1[m][p] * U1[kk][qq];
                if (cc != 0.f) {
                    A[p * 3 + qq] -= R1[i] * cc;
                    Bp[p * 3 + qq] -= R2[i] * cc;
                }
            }
    }
#pragma unroll
    for (int i = 0; i < 4; ++i) {
        const int m = i & 1, kk = i >> 1;
#pragma unroll
        for (int j = 0; j < 4; ++j) {
            const int nn = j & 1, ll = j >> 1;
            const float cv = Cm[i * 4 + j];
#pragma unroll
            for (int p = 0; p < 2; ++p)
#pragma unroll
                for (int qq = 0; qq < 2; ++qq)
#pragma unroll
                    for (int rr = 0; rr < 2; ++rr)
#pragma unroll
                        for (int ss = 0; ss < 2; ++ss) {
                            const float cc = U1[m][p] * U1[kk][qq]
                                           * U1[nn][rr] * U1[ll][ss];
                            if (cc != 0.f)
                                Xc[p * 8 + qq * 4 + rr * 2 + ss] -= cv * cc;
                        }
        }
    }

    // ---- predicated stores: lane q stores planes t with (t&3)==q ----
    char* cb = (char*)coef;
#pragma unroll
    for (int t = 0; t < 9; ++t)
        if ((t & 3) == q) *(float*)(cb + (size_t)t * HW * 4 + voff) = A[t];
#pragma unroll
    for (int t = 0; t < 9; ++t)
        if (((t + 9) & 3) == q)
            *(float*)(cb + (size_t)(t + 9) * HW * 4 + voff) = Bp[t];
#pragma unroll
    for (int t = 0; t < 16; ++t)
        if (((t + 18) & 3) == q)
            *(float*)(cb + (size_t)(t + 18) * HW * 4 + voff) = Xc[t];
}

// ---------------------------------------------------------------------------
// Phase 2 (R13): eval + softmax, 4 lanes/pixel, 8 depths/lane. Fast path is
// 31 fmaf (two biquadratic Horners + one multilinear tree); masks are inside
// the coefficients. rcp+Newton projections (no IEEE div chains). Slow path
// (exact direct regather with full mask logic) guards any window deviation.
// ---------------------------------------------------------------------------
__global__ __launch_bounds__(256) void evalsm2_kernel(
    const float* __restrict__ feats,
    const float* __restrict__ dvals,
    const float* __restrict__ wreg,
    const float* __restrict__ mats,
    const float* __restrict__ coef,    // [34][HW]
    float* __restrict__ out)           // depth[HW] | conf[HW] | prob[D][HW]
{
    const unsigned tid = blockIdx.x * 256u + threadIdx.x;
    const unsigned n = tid >> 2;           // pixel
    const int q = (int)(tid & 3u);         // depth quarter
    const int d0 = q * 8;
    const int y = (int)(n / NW);
    const int x = (int)(n - (unsigned)y * NW);
    const float fx = (float)x, fy = (float)y;
    const unsigned voff = n * 4u;

    float rxv[2], ryv[2], rzv[2], t0v[2], t1v[2], t2v[2];
#pragma unroll
    for (int v = 0; v < 2; ++v) {
        const float* m = mats + v * 12;
        rxv[v] = fmaf(m[0], fx, fmaf(m[1], fy, m[2]));
        ryv[v] = fmaf(m[3], fx, fmaf(m[4], fy, m[5]));
        rzv[v] = fmaf(m[6], fx, fmaf(m[7], fy, m[8]));
        t0v[v] = m[9]; t1v[v] = m[10]; t2v[v] = m[11];
    }

    // reference window anchor (same expressions as stats4 -> same bits)
    const float dep0 = *(const float*)((const char*)dvals + voff);
    int x0r[2], y0r[2];
#pragma unroll
    for (int v = 0; v < 2; ++v) {
        float pxn = fmaf(rxv[v], dep0, t0v[v]);
        float pyn = fmaf(ryv[v], dep0, t1v[v]);
        float z   = fmaf(rzv[v], dep0, t2v[v]);
        z = (fabsf(z) < 1e-6f) ? 1e-6f : z;
        float ri = frcp(z);
        x0r[v] = (int)floorf(pxn * ri);
        y0r[v] = (int)floorf(pyn * ri);
    }

    // 34 coefficient loads (SGPR bases + shared voffset)
    const char* cb = (const char*)coef;
    float A[9], Bp[9], Xc[16];
#pragma unroll
    for (int k = 0; k < 9; ++k) {
        A[k]  = *(const float*)(cb + (size_t)k * HW * 4 + voff);
        Bp[k] = *(const float*)(cb + (size_t)(k + 9) * HW * 4 + voff);
    }
#pragma unroll
    for (int k = 0; k < 16; ++k)
        Xc[k] = *(const float*)(cb + (size_t)(k + 18) * HW * 4 + voff);

    const char* f1b = (const char*)(feats + (size_t)1 * NC * HW);
    const char* f2b = (const char*)(feats + (size_t)2 * NC * HW);

    // ---- 8 depth evals ----
    float c[8], dv[8];
    float mx = -INFINITY;
#pragma unroll
    for (int ck = 0; ck < 2; ++ck) {
        float pxs[2][4], pys[2][4];
#pragma unroll
        for (int dd = 0; dd < 4; ++dd) {
            const float depth = *(const float*)((const char*)dvals +
                                 (size_t)(d0 + ck * 4 + dd) * HW * 4 + voff);
            dv[ck * 4 + dd] = depth;
#pragma unroll
            for (int v = 0; v < 2; ++v) {
                float pxn = fmaf(rxv[v], depth, t0v[v]);
                float pyn = fmaf(ryv[v], depth, t1v[v]);
                float z   = fmaf(rzv[v], depth, t2v[v]);
                z = (fabsf(z) < 1e-6f) ? 1e-6f : z;
                float ri = frcp(z);
                pxs[v][dd] = pxn * ri;
                pys[v][dd] = pyn * ri;
            }
        }
#pragma unroll
        for (int dd = 0; dd < 4; ++dd) {
            float wx[2], wy[2];
            int ax0[2], ay0[2];
            bool fast = true;
#pragma unroll
            for (int v = 0; v < 2; ++v) {
                float px = pxs[v][dd], py = pys[v][dd];
                float x0f = floorf(px), y0f = floorf(py);
                wx[v] = px - x0f;
                wy[v] = py - y0f;
                int x0 = (int)x0f, y0 = (int)y0f;
                ax0[v] = x0; ay0[v] = y0;
                fast = fast && (x0 == x0r[v]) && (y0 == y0r[v]);
            }

            float cst;
            if (fast) {
                const float wx0 = wx[0], wy0 = wy[0];
                const float wx1 = wx[1], wy1 = wy[1];
                float a0 = fmaf(wy0, fmaf(wy0, A[2], A[1]), A[0]);
                float a1 = fmaf(wy0, fmaf(wy0, A[5], A[4]), A[3]);
                float a2 = fmaf(wy0, fmaf(wy0, A[8], A[7]), A[6]);
                float PA = fmaf(wx0, fmaf(wx0, a2, a1), a0);
                float b0 = fmaf(wy1, fmaf(wy1, Bp[2], Bp[1]), Bp[0]);
                float b1 = fmaf(wy1, fmaf(wy1, Bp[5], Bp[4]), Bp[3]);
                float b2 = fmaf(wy1, fmaf(wy1, Bp[8], Bp[7]), Bp[6]);
                float PB = fmaf(wx1, fmaf(wx1, b2, b1), b0);
                float y0_ = fmaf(wy1, Xc[1], Xc[0]);
                float y1_ = fmaf(wy1, Xc[3], Xc[2]);
                float y2_ = fmaf(wy1, Xc[5], Xc[4]);
                float y3_ = fmaf(wy1, Xc[7], Xc[6]);
                float y4_ = fmaf(wy1, Xc[9], Xc[8]);
                float y5_ = fmaf(wy1, Xc[11], Xc[10]);
                float y6_ = fmaf(wy1, Xc[13], Xc[12]);
                float y7_ = fmaf(wy1, Xc[15], Xc[14]);
                float z0_ = fmaf(wx1, y1_, y0_);
                float z1_ = fmaf(wx1, y3_, y2_);
                float z2_ = fmaf(wx1, y5_, y4_);
                float z3_ = fmaf(wx1, y7_, y6_);
                float w0_ = fmaf(wy0, z1_, z0_);
                float w1_ = fmaf(wy0, z3_, z2_);
                float Xv = fmaf(wx0, w1_, w0_);
                cst = (2.f / 9.f) * (PA + PB + Xv);
            } else {
                // slow path: exact direct regather with full mask logic
                float al[2][4];
                unsigned so[2][4];
#pragma unroll
                for (int v = 0; v < 2; ++v) {
                    int x0 = ax0[v], y0 = ay0[v];
                    bool vx0 = (x0 >= 0) && (x0 < NW);
                    bool vx1 = (x0 + 1 >= 0) && (x0 + 1 < NW);
                    bool vy0 = (y0 >= 0) && (y0 < NH);
                    bool vy1 = (y0 + 1 >= 0) && (y0 + 1 < NH);
                    float wxx = wx[v], wyy = wy[v];
                    al[v][0] = (1.f - wxx) * (1.f - wyy) * ((vx0 && vy0) ? 1.f : 0.f);
                    al[v][1] = wxx * (1.f - wyy) * ((vx1 && vy0) ? 1.f : 0.f);
                    al[v][2] = (1.f - wxx) * wyy * ((vx0 && vy1) ? 1.f : 0.f);
                    al[v][3] = wxx * wyy * ((vx1 && vy1) ? 1.f : 0.f);
                    int cx0 = min(max(x0, 0), NW - 1);
                    int cx1 = min(max(x0 + 1, 0), NW - 1);
                    int cy0 = min(max(y0, 0), NH - 1);
                    int cy1 = min(max(y0 + 1, 0), NH - 1);
                    so[v][0] = (unsigned)(cy0 * NW + cx0) * 4u;
                    so[v][1] = (unsigned)(cy0 * NW + cx1) * 4u;
                    so[v][2] = (unsigned)(cy1 * NW + cx0) * 4u;
                    so[v][3] = (unsigned)(cy1 * NW + cx1) * 4u;
                }
                float acc = 0.f;
#pragma unroll
                for (int cc = 0; cc < NC; ++cc) {
                    const char* frc = (const char*)feats + (size_t)cc * HW * 4;
                    const char* f1c = f1b + (size_t)cc * HW * 4;
                    const char* f2c = f2b + (size_t)cc * HW * 4;
                    float r = *(const float*)(frc + voff);
                    float s1 = 0.f, s2 = 0.f;
#pragma unroll
                    for (int i = 0; i < 4; ++i) {
                        s1 = fmaf(*(const float*)(f1c + so[0][i]), al[0][i], s1);
                        s2 = fmaf(*(const float*)(f2c + so[1][i]), al[1][i], s2);
                    }
                    float e = r * r + s1 * s1 + s2 * s2
                            - r * s1 - r * s2 - s1 * s2;
                    acc = fmaf(wreg[cc], e, acc);
                }
                cst = (2.f / 9.f) * acc;
            }
            c[ck * 4 + dd] = cst;
            mx = fmaxf(mx, cst);
        }
    }

    // ---- cross-lane softmax over the 4-lane group ----
    mx = fmaxf(mx, __shfl_xor(mx, 1));
    mx = fmaxf(mx, __shfl_xor(mx, 2));
    float ssum = 0.f;
#pragma unroll
    for (int i = 0; i < 8; ++i) {
        float e = expf(c[i] - mx);
        c[i] = e;
        ssum += e;
    }
    ssum += __shfl_xor(ssum, 1);
    ssum += __shfl_xor(ssum, 2);
    float inv = 1.f / ssum;

    float* prob = out + 2 * HW;
    float depth_acc = 0.f, didx_acc = 0.f;
#pragma unroll
    for (int i = 0; i < 8; ++i) {
        float pv = c[i] * inv;
        c[i] = pv;
        *(float*)((char*)prob + (size_t)(d0 + i) * HW * 4 + voff) = pv;
        depth_acc = fmaf(pv, dv[i], depth_acc);
        didx_acc = fmaf(pv, (float)(d0 + i), didx_acc);
    }
    depth_acc += __shfl_xor(depth_acc, 1);
    depth_acc += __shfl_xor(depth_acc, 2);
    didx_acc += __shfl_xor(didx_acc, 1);
    didx_acc += __shfl_xor(didx_acc, 2);

    int di = (int)didx_acc;            // trunc toward zero == astype(int32)
    di = min(max(di, 0), ND - 1);
    float pdi = 0.f, pdi1 = 0.f;
#pragma unroll
    for (int i = 0; i < 8; ++i) {
        pdi  = (d0 + i == di)     ? c[i] : pdi;
        pdi1 = (d0 + i == di + 1) ? c[i] : pdi1;
    }
    pdi  += __shfl_xor(pdi, 1);
    pdi  += __shfl_xor(pdi, 2);
    pdi1 += __shfl_xor(pdi1, 1);
    pdi1 += __shfl_xor(pdi1, 2);

    if (q == 0) {
        out[n] = depth_acc;
        out[HW + n] = pdi + pdi1;
    }
}

// ---------------------------------------------------------------------------
// Fallback (R11 fused kernel) if ws can't hold the coefficient planes.
// ---------------------------------------------------------------------------
__global__ __launch_bounds__(64) void fused_kernel(
    const float* __restrict__ feats,
    const float* __restrict__ dvals,
    const float* __restrict__ wreg,
    const float* __restrict__ mats,
    float* __restrict__ out)
{
    const unsigned n = blockIdx.x * 64u + threadIdx.x;
    const int y = (int)(n / NW);
    const int x = (int)(n - (unsigned)y * NW);
    const float fx = (float)x, fy = (float)y;
    const unsigned voff = n * 4u;

    float rxv[2], ryv[2], rzv[2], t0v[2], t1v[2], t2v[2];
#pragma unroll
    for (int v = 0; v < 2; ++v) {
        const float* m = mats + v * 12;
        rxv[v] = fmaf(m[0], fx, fmaf(m[1], fy, m[2]));
        ryv[v] = fmaf(m[3], fx, fmaf(m[4], fy, m[5]));
        rzv[v] = fmaf(m[6], fx, fmaf(m[7], fy, m[8]));
        t0v[v] = m[9]; t1v[v] = m[10]; t2v[v] = m[11];
    }

    const float dep0 = *(const float*)((const char*)dvals + voff);
    int x0r[2], y0r[2];
    unsigned co[2][4];
#pragma unroll
    for (int v = 0; v < 2; ++v) {
        float pxn = fmaf(rxv[v], dep0, t0v[v]);
        float pyn = fmaf(ryv[v], dep0, t1v[v]);
        float z   = fmaf(rzv[v], dep0, t2v[v]);
        z = (fabsf(z) < 1e-6f) ? 1e-6f : z;
        float px = pxn / z, py = pyn / z;
        int x0 = (int)floorf(px), y0 = (int)floorf(py);
        x0r[v] = x0; y0r[v] = y0;
        int cx0 = min(max(x0, 0), NW - 1);
        int cx1 = min(max(x0 + 1, 0), NW - 1);
        int cy0 = min(max(y0, 0), NH - 1);
        int cy1 = min(max(y0 + 1, 0), NH - 1);
        co[v][0] = (unsigned)(cy0 * NW + cx0) * 4u;
        co[v][1] = (unsigned)(cy0 * NW + cx1) * 4u;
        co[v][2] = (unsigned)(cy1 * NW + cx0) * 4u;
        co[v][3] = (unsigned)(cy1 * NW + cx1) * 4u;
    }

    float G1[10], G2[10], Cm[16], R1[4], R2[4];
    float r2 = 0.f;
#pragma unroll
    for (int k = 0; k < 10; ++k) { G1[k] = 0.f; G2[k] = 0.f; }
#pragma unroll
    for (int k = 0; k < 16; ++k) Cm[k] = 0.f;
#pragma unroll
    for (int k = 0; k < 4; ++k) { R1[k] = 0.f; R2[k] = 0.f; }

    const char* f1b = (const char*)(feats + (size_t)1 * NC * HW);
    const char* f2b = (const char*)(feats + (size_t)2 * NC * HW);
#pragma unroll
    for (int c = 0; c < NC; ++c) {
        const char* frc = (const char*)feats + (size_t)c * HW * 4;
        const char* f1c = f1b + (size_t)c * HW * 4;
        const char* f2c = f2b + (size_t)c * HW * 4;
        float r = *(const float*)(frc + voff);
        float g1[4], g2[4];
#pragma unroll
        for (int i = 0; i < 4; ++i) {
            g1[i] = *(const float*)(f1c + co[0][i]);
            g2[i] = *(const float*)(f2c + co[1][i]);
        }
        float w = wreg[c];
        float wr = w * r;
        r2 = fmaf(wr, r, r2);
        float wg1[4], wg2[4];
#pragma unroll
        for (int i = 0; i < 4; ++i) { wg1[i] = w * g1[i]; wg2[i] = w * g2[i]; }
#pragma unroll
        for (int i = 0; i < 4; ++i) {
            R1[i] = fmaf(wr, g1[i], R1[i]);
            R2[i] = fmaf(wr, g2[i], R2[i]);
        }
#pragma unroll
        for (int i = 0; i < 4; ++i)
#pragma unroll
            for (int j = i; j < 4; ++j) {
                G1[SYM(i, j)] = fmaf(wg1[i], g1[j], G1[SYM(i, j)]);
                G2[SYM(i, j)] = fmaf(wg2[i], g2[j], G2[SYM(i, j)]);
            }
#pragma unroll
        for (int i = 0; i < 4; ++i)
#pragma unroll
            for (int j = 0; j < 4; ++j)
                Cm[i * 4 + j] = fmaf(wg1[i], g2[j], Cm[i * 4 + j]);
    }
#pragma unroll
    for (int i = 0; i < 4; ++i)
#pragma unroll
        for (int j = i + 1; j < 4; ++j) {
            G1[SYM(i, j)] += G1[SYM(i, j)];
            G2[SYM(i, j)] += G2[SYM(i, j)];
        }

    float c[ND];
    float mx = -INFINITY;
#pragma unroll
    for (int ck = 0; ck < ND / 4; ++ck) {
        float pxs[2][4], pys[2][4];
#pragma unroll
        for (int dd = 0; dd < 4; ++dd) {
            const float depth = *(const float*)((const char*)dvals +
                                 (size_t)(ck * 4 + dd) * HW * 4 + voff);
#pragma unroll
            for (int v = 0; v < 2; ++v) {
                float pxn = fmaf(rxv[v], depth, t0v[v]);
                float pyn = fmaf(ryv[v], depth, t1v[v]);
                float z   = fmaf(rzv[v], depth, t2v[v]);
                z = (fabsf(z) < 1e-6f) ? 1e-6f : z;
                pxs[v][dd] = pxn / z;
                pys[v][dd] = pyn / z;
            }
        }
#pragma unroll
        for (int dd = 0; dd < 4; ++dd) {
            float al[2][4];
            int ax0[2], ay0[2];
            bool fast = true;
#pragma unroll
            for (int v = 0; v < 2; ++v) {
                float px = pxs[v][dd], py = pys[v][dd];
                float x0f = floorf(px), y0f = floorf(py);
                float wx = px - x0f, wy = py - y0f;
                int x0 = (int)x0f, y0 = (int)y0f;
                ax0[v] = x0; ay0[v] = y0;
                fast = fast && (x0 == x0r[v]) && (y0 == y0r[v]);
                bool vx0 = (x0 >= 0) && (x0 < NW);
                bool vx1 = (x0 + 1 >= 0) && (x0 + 1 < NW);
                bool vy0 = (y0 >= 0) && (y0 < NH);
                bool vy1 = (y0 + 1 >= 0) && (y0 + 1 < NH);
                al[v][0] = (1.f - wx) * (1.f - wy) * ((vx0 && vy0) ? 1.f : 0.f);
                al[v][1] = wx * (1.f - wy) * ((vx1 && vy0) ? 1.f : 0.f);
                al[v][2] = (1.f - wx) * wy * ((vx0 && vy1) ? 1.f : 0.f);
                al[v][3] = wx * wy * ((vx1 && vy1) ? 1.f : 0.f);
            }

            float cst;
            if (fast) {
                float q1 = 0.f, q2 = 0.f;
#pragma unroll
                for (int i = 0; i < 4; ++i)
#pragma unroll
                    for (int j = i; j < 4; ++j) {
                        q1 = fmaf(G1[SYM(i, j)], al[0][i] * al[0][j], q1);
                        q2 = fmaf(G2[SYM(i, j)], al[1][i] * al[1][j], q2);
                    }
                float qc = 0.f;
#pragma unroll
                for (int i = 0; i < 4; ++i)
#pragma unroll
                    for (int j = 0; j < 4; ++j)
                        qc = fmaf(Cm[i * 4 + j], al[0][i] * al[1][j], qc);
                float lr = 0.f;
#pragma unroll
                for (int i = 0; i < 4; ++i) {
                    lr = fmaf(R1[i], al[0][i], lr);
                    lr = fmaf(R2[i], al[1][i], lr);
                }
                cst = (2.f / 9.f) * (r2 + q1 + q2 - lr - qc);
            } else {
                unsigned so[2][4];
#pragma unroll
                for (int v = 0; v < 2; ++v) {
                    int cx0 = min(max(ax0[v], 0), NW - 1);
                    int cx1 = min(max(ax0[v] + 1, 0), NW - 1);
                    int cy0 = min(max(ay0[v], 0), NH - 1);
                    int cy1 = min(max(ay0[v] + 1, 0), NH - 1);
                    so[v][0] = (unsigned)(cy0 * NW + cx0) * 4u;
                    so[v][1] = (unsigned)(cy0 * NW + cx1) * 4u;
                    so[v][2] = (unsigned)(cy1 * NW + cx0) * 4u;
                    so[v][3] = (unsigned)(cy1 * NW + cx1) * 4u;
                }
                float acc = 0.f;
#pragma unroll
                for (int cc = 0; cc < NC; ++cc) {
                    const char* frc = (const char*)feats + (size_t)cc * HW * 4;
                    const char* f1c = f1b + (size_t)cc * HW * 4;
                    const char* f2c = f2b + (size_t)cc * HW * 4;
                    float r = *(const float*)(frc + voff);
                    float s1 = 0.f, s2 = 0.f;
#pragma unroll
                    for (int i = 0; i < 4; ++i) {
                        s1 = fmaf(*(const float*)(f1c + so[0][i]), al[0][i], s1);
                        s2 = fmaf(*(const float*)(f2c + so[1][i]), al[1][i], s2);
                    }
                    float e = r * r + s1 * s1 + s2 * s2
                            - r * s1 - r * s2 - s1 * s2;
                    acc = fmaf(wreg[cc], e, acc);
                }
                cst = (2.f / 9.f) * acc;
            }
            c[ck * 4 + dd] = cst;
            mx = fmaxf(mx, cst);
        }
    }

    float ssum = 0.f;
#pragma unroll
    for (int d = 0; d < ND; ++d) {
        float e = expf(c[d] - mx);
        c[d] = e;
        ssum += e;
    }
    float inv = 1.f / ssum;
    float* prob = out + 2 * HW;
    float depth_acc = 0.f, didx_acc = 0.f;
#pragma unroll
    for (int d = 0; d < ND; ++d) {
        float pv = c[d] * inv;
        c[d] = pv;
        *(float*)((char*)prob + (size_t)d * HW * 4 + voff) = pv;
        float dvv = *(const float*)((const char*)dvals + (size_t)d * HW * 4 + voff);
        depth_acc = fmaf(pv, dvv, depth_acc);
        didx_acc = fmaf(pv, (float)d, didx_acc);
    }
    int di = (int)didx_acc;
    di = min(max(di, 0), ND - 1);
    float pdi = 0.f, pdi1 = 0.f;
#pragma unroll
    for (int d = 0; d < ND; ++d) {
        pdi = (d == di) ? c[d] : pdi;
        pdi1 = (d == di + 1) ? c[d] : pdi1;
    }
    out[n] = depth_acc;
    out[HW + n] = pdi + pdi1;
}

extern "C" void kernel_launch(void* const* d_in, const int* in_sizes, int n_in,
                              void* d_out, int out_size, void* d_ws, size_t ws_size,
                              hipStream_t stream) {
    const float* feats = (const float*)d_in[0];
    const float* pm    = (const float*)d_in[1];
    const float* dvals = (const float*)d_in[2];
    const float* wreg  = (const float*)d_in[3];
    float* out = (float*)d_out;
    float* mats = (float*)d_ws;                  // 24 floats

    proj_setup_kernel<<<1, 64, 0, stream>>>(pm, mats);

    if (ws_size >= COEF_OFF + COEF_BYTES) {
        float* coef = (float*)((char*)d_ws + COEF_OFF);
        stats4_kernel<<<HW * 4 / 256, 256, 0, stream>>>(feats, dvals, wreg,
                                                        mats, coef);
        evalsm2_kernel<<<HW * 4 / 256, 256, 0, stream>>>(feats, dvals, wreg,
                                                         mats, coef, out);
    } else {
        fused_kernel<<<HW / 64, 64, 0, stream>>>(feats, dvals, wreg, mats,
                                                 out);
    }
}

// Round 14
// 28.461 us; speedup vs baseline: 1.9732x; 1.2207x over previous
//
#include <hip/hip_runtime.h>
#include <math.h>

namespace {
constexpr int NV = 3;    // views
constexpr int NC = 16;   // channels
constexpr int ND = 32;   // depths
constexpr int NH = 256;
constexpr int NW = 320;
constexpr int HW = NH * NW;       // 81920
#define SYM(i, j) ((i) * 4 + (j) - (i) * ((i) + 1) / 2)
}

// rcp + 1 Newton step (same sequence everywhere -> consistent anchors).
__device__ __forceinline__ float frcp(float z) {
    float r = __builtin_amdgcn_rcpf(z);
    return r * fmaf(-z, r, 2.0f);
}

// ---------------------------------------------------------------------------
// R14: ONE kernel. 4 lanes/pixel.
//  Phase 0: per-thread proj math: P_v = [K E]_3x4 (+row3), inv(P0) via the
//           STATIC adjugate (no runtime-indexed pivoting -> no scratch,
//           rule #20), M_v = P_v inv(P0) -> rot,trans per src view.
//  Phase 1: stats — lane q gathers its 4 channels' corner values (d0-window,
//           masks folded), accumulates quad-form sums, 2-step butterfly
//           allreduce (after which EVERY lane holds all 45 sums), basis
//           change -> A[9],Bp[9],Xc[16] polynomial coeffs in registers.
//  Phase 2: eval — lane q evaluates depths 8q..8q+7 (31-fmaf fast path,
//           exact slow-path regather on window deviation), cross-lane
//           softmax + depth/conf via __shfl_xor butterflies, direct stores.
// No LDS, no workspace, no intermediate global traffic, single launch.
// ---------------------------------------------------------------------------
__global__ __launch_bounds__(256) void mega_kernel(
    const float* __restrict__ feats,   // [V][C][HW]
    const float* __restrict__ pm,      // [V][2][4][4]
    const float* __restrict__ dvals,   // [D][HW]
    const float* __restrict__ wreg,    // [C]
    float* __restrict__ out)           // depth[HW] | conf[HW] | prob[D][HW]
{
    const unsigned tid = blockIdx.x * 256u + threadIdx.x;
    const unsigned n = tid >> 2;       // pixel
    const int q = (int)(tid & 3u);     // lane-in-group: channel & depth quarter
    const int y = (int)(n / NW);
    const int x = (int)(n - (unsigned)y * NW);
    const float fx = (float)x, fy = (float)y;
    const unsigned voff = n * 4u;

    // ---------------- phase 0: projection matrices (uniform math) ----------
    // P[v] = [ K(:3,:3)*E(:3,:4) ; E_row3 ]
    float P[NV][4][4];
#pragma unroll
    for (int v = 0; v < NV; ++v) {
        const float* E = pm + v * 2 * 16;
        const float* K = pm + v * 2 * 16 + 16;
#pragma unroll
        for (int j = 0; j < 4; ++j) P[v][3][j] = E[12 + j];
#pragma unroll
        for (int i = 0; i < 3; ++i)
#pragma unroll
            for (int j = 0; j < 4; ++j) {
                float acc = 0.f;
#pragma unroll
                for (int k = 0; k < 3; ++k) acc += K[i * 4 + k] * E[k * 4 + j];
                P[v][i][j] = acc;
            }
    }
    // inv(P0) via static adjugate (all indices compile-time)
    float Inv[4][4];
    {
        const float m00 = P[0][0][0], m01 = P[0][0][1], m02 = P[0][0][2], m03 = P[0][0][3];
        const float m10 = P[0][1][0], m11 = P[0][1][1], m12 = P[0][1][2], m13 = P[0][1][3];
        const float m20 = P[0][2][0], m21 = P[0][2][1], m22 = P[0][2][2], m23 = P[0][2][3];
        const float m30 = P[0][3][0], m31 = P[0][3][1], m32 = P[0][3][2], m33 = P[0][3][3];
        const float s0 = m00 * m11 - m10 * m01;
        const float s1 = m00 * m12 - m10 * m02;
        const float s2 = m00 * m13 - m10 * m03;
        const float s3 = m01 * m12 - m11 * m02;
        const float s4 = m01 * m13 - m11 * m03;
        const float s5 = m02 * m13 - m12 * m03;
        const float c5 = m22 * m33 - m32 * m23;
        const float c4 = m21 * m33 - m31 * m23;
        const float c3 = m21 * m32 - m31 * m22;
        const float c2 = m20 * m33 - m30 * m23;
        const float c1 = m20 * m32 - m30 * m22;
        const float c0 = m20 * m31 - m30 * m21;
        const float det = s0 * c5 - s1 * c4 + s2 * c3 + s3 * c2 - s4 * c1 + s5 * c0;
        const float id = 1.f / det;
        Inv[0][0] = ( m11 * c5 - m12 * c4 + m13 * c3) * id;
        Inv[0][1] = (-m01 * c5 + m02 * c4 - m03 * c3) * id;
        Inv[0][2] = ( m31 * s5 - m32 * s4 + m33 * s3) * id;
        Inv[0][3] = (-m21 * s5 + m22 * s4 - m23 * s3) * id;
        Inv[1][0] = (-m10 * c5 + m12 * c2 - m13 * c1) * id;
        Inv[1][1] = ( m00 * c5 - m02 * c2 + m03 * c1) * id;
        Inv[1][2] = (-m30 * s5 + m32 * s2 - m33 * s1) * id;
        Inv[1][3] = ( m20 * s5 - m22 * s2 + m23 * s1) * id;
        Inv[2][0] = ( m10 * c4 - m11 * c2 + m13 * c0) * id;
        Inv[2][1] = (-m00 * c4 + m01 * c2 - m03 * c0) * id;
        Inv[2][2] = ( m30 * s4 - m31 * s2 + m33 * s0) * id;
        Inv[2][3] = (-m20 * s4 + m21 * s2 - m23 * s0) * id;
        Inv[3][0] = (-m10 * c3 + m11 * c1 - m12 * c0) * id;
        Inv[3][1] = ( m00 * c3 - m01 * c1 + m02 * c0) * id;
        Inv[3][2] = (-m30 * s3 + m31 * s1 - m32 * s0) * id;
        Inv[3][3] = ( m20 * s3 - m21 * s1 + m22 * s0) * id;
    }
    // M_v = P_v * Inv -> per-view rot*(x,y,1) and translation
    float rxv[2], ryv[2], rzv[2], t0v[2], t1v[2], t2v[2];
#pragma unroll
    for (int v = 0; v < 2; ++v) {
        float M[3][4];
#pragma unroll
        for (int i = 0; i < 3; ++i)
#pragma unroll
            for (int j = 0; j < 4; ++j) {
                float acc = 0.f;
#pragma unroll
                for (int k = 0; k < 4; ++k) acc += P[v + 1][i][k] * Inv[k][j];
                M[i][j] = acc;
            }
        rxv[v] = fmaf(M[0][0], fx, fmaf(M[0][1], fy, M[0][2]));
        ryv[v] = fmaf(M[1][0], fx, fmaf(M[1][1], fy, M[1][2]));
        rzv[v] = fmaf(M[2][0], fx, fmaf(M[2][1], fy, M[2][2]));
        t0v[v] = M[0][3]; t1v[v] = M[1][3]; t2v[v] = M[2][3];
    }

    // ---------------- phase 1: stats -> polynomial coefficients ------------
    const float dep0 = *(const float*)((const char*)dvals + voff); // plane 0
    int x0r[2], y0r[2];
    unsigned co[2][4];
    float mk[2][4];
#pragma unroll
    for (int v = 0; v < 2; ++v) {
        float pxn = fmaf(rxv[v], dep0, t0v[v]);
        float pyn = fmaf(ryv[v], dep0, t1v[v]);
        float z   = fmaf(rzv[v], dep0, t2v[v]);
        z = (fabsf(z) < 1e-6f) ? 1e-6f : z;
        float ri = frcp(z);
        float px = pxn * ri, py = pyn * ri;
        int x0 = (int)floorf(px), y0 = (int)floorf(py);
        x0r[v] = x0; y0r[v] = y0;
        bool vx0 = (x0 >= 0) && (x0 < NW);
        bool vx1 = (x0 + 1 >= 0) && (x0 + 1 < NW);
        bool vy0 = (y0 >= 0) && (y0 < NH);
        bool vy1 = (y0 + 1 >= 0) && (y0 + 1 < NH);
        mk[v][0] = (vx0 && vy0) ? 1.f : 0.f;
        mk[v][1] = (vx1 && vy0) ? 1.f : 0.f;
        mk[v][2] = (vx0 && vy1) ? 1.f : 0.f;
        mk[v][3] = (vx1 && vy1) ? 1.f : 0.f;
        int cx0 = min(max(x0, 0), NW - 1);
        int cx1 = min(max(x0 + 1, 0), NW - 1);
        int cy0 = min(max(y0, 0), NH - 1);
        int cy1 = min(max(y0 + 1, 0), NH - 1);
        co[v][0] = (unsigned)(cy0 * NW + cx0) * 4u;
        co[v][1] = (unsigned)(cy0 * NW + cx1) * 4u;
        co[v][2] = (unsigned)(cy1 * NW + cx0) * 4u;
        co[v][3] = (unsigned)(cy1 * NW + cx1) * 4u;
    }

    float G1[10], G2[10], Cm[16], R1[4], R2[4];
    float r2 = 0.f;
#pragma unroll
    for (int k = 0; k < 10; ++k) { G1[k] = 0.f; G2[k] = 0.f; }
#pragma unroll
    for (int k = 0; k < 16; ++k) Cm[k] = 0.f;
#pragma unroll
    for (int k = 0; k < 4; ++k) { R1[k] = 0.f; R2[k] = 0.f; }

    const char* fb = (const char*)feats;
    const char* f1b = fb + (size_t)1 * NC * HW * 4;
    const char* f2b = fb + (size_t)2 * NC * HW * 4;
#pragma unroll
    for (int c4 = 0; c4 < 4; ++c4) {
        const int c = q * 4 + c4;
        const char* frc = fb + (size_t)c * HW * 4;
        const char* f1c = f1b + (size_t)c * HW * 4;
        const char* f2c = f2b + (size_t)c * HW * 4;
        float r = *(const float*)(frc + voff);
        float g1[4], g2[4];
#pragma unroll
        for (int i = 0; i < 4; ++i) {
            g1[i] = *(const float*)(f1c + co[0][i]) * mk[0][i];  // mask folded
            g2[i] = *(const float*)(f2c + co[1][i]) * mk[1][i];
        }
        float w = wreg[c];
        float wr = w * r;
        r2 = fmaf(wr, r, r2);
        float wg1[4], wg2[4];
#pragma unroll
        for (int i = 0; i < 4; ++i) { wg1[i] = w * g1[i]; wg2[i] = w * g2[i]; }
#pragma unroll
        for (int i = 0; i < 4; ++i) {
            R1[i] = fmaf(wr, g1[i], R1[i]);
            R2[i] = fmaf(wr, g2[i], R2[i]);
        }
#pragma unroll
        for (int i = 0; i < 4; ++i)
#pragma unroll
            for (int j = i; j < 4; ++j) {
                G1[SYM(i, j)] = fmaf(wg1[i], g1[j], G1[SYM(i, j)]);
                G2[SYM(i, j)] = fmaf(wg2[i], g2[j], G2[SYM(i, j)]);
            }
#pragma unroll
        for (int i = 0; i < 4; ++i)
#pragma unroll
            for (int j = 0; j < 4; ++j)
                Cm[i * 4 + j] = fmaf(wg1[i], g2[j], Cm[i * 4 + j]);
    }

    // butterfly allreduce: after this every lane holds the full 45 sums
#pragma unroll
    for (int k = 0; k < 10; ++k) {
        G1[k] += __shfl_xor(G1[k], 1); G1[k] += __shfl_xor(G1[k], 2);
        G2[k] += __shfl_xor(G2[k], 1); G2[k] += __shfl_xor(G2[k], 2);
    }
#pragma unroll
    for (int k = 0; k < 16; ++k) {
        Cm[k] += __shfl_xor(Cm[k], 1); Cm[k] += __shfl_xor(Cm[k], 2);
    }
#pragma unroll
    for (int k = 0; k < 4; ++k) {
        R1[k] += __shfl_xor(R1[k], 1); R1[k] += __shfl_xor(R1[k], 2);
        R2[k] += __shfl_xor(R2[k], 1); R2[k] += __shfl_xor(R2[k], 2);
    }
    r2 += __shfl_xor(r2, 1); r2 += __shfl_xor(r2, 2);

    // basis change: quad-form -> polynomial coefficients (in registers)
    static constexpr float U2[3][3] = {{1.f,-2.f,1.f},{0.f,1.f,-1.f},{0.f,0.f,1.f}};
    static constexpr float U1[2][2] = {{1.f,-1.f},{0.f,1.f}};
    float A[9], Bp[9], Xc[16];
#pragma unroll
    for (int k = 0; k < 9; ++k) { A[k] = 0.f; Bp[k] = 0.f; }
#pragma unroll
    for (int k = 0; k < 16; ++k) Xc[k] = 0.f;
    A[0] = r2;
#pragma unroll
    for (int i = 0; i < 4; ++i) {
#pragma unroll
        for (int j = 0; j < 4; ++j) {
            const int lo = i < j ? i : j, hi = i < j ? j : i;
            const float g1v = G1[SYM(lo, hi)];
            const float g2v = G2[SYM(lo, hi)];
            const int m = i & 1, kk = i >> 1, nn = j & 1, ll = j >> 1;
#pragma unroll
            for (int p = 0; p < 3; ++p)
#pragma unroll
                for (int qq = 0; qq < 3; ++qq) {
                    const float cc = U2[m + nn][p] * U2[kk + ll][qq];
                    if (cc != 0.f) {
                        A[p * 3 + qq] += g1v * cc;
                        Bp[p * 3 + qq] += g2v * cc;
                    }
                }
        }
    }
#pragma unroll
    for (int i = 0; i < 4; ++i) {
        const int m = i & 1, kk = i >> 1;
#pragma unroll
        for (int p = 0; p < 2; ++p)
#pragma unroll
            for (int qq = 0; qq < 2; ++qq) {
                const float cc = U1[m][p] * U1[kk][qq];
                if (cc != 0.f) {
                    A[p * 3 + qq] -= R1[i] * cc;
                    Bp[p * 3 + qq] -= R2[i] * cc;
                }
            }
    }
#pragma unroll
    for (int i = 0; i < 4; ++i) {
        const int m = i & 1, kk = i >> 1;
#pragma unroll
        for (int j = 0; j < 4; ++j) {
            const int nn = j & 1, ll = j >> 1;
            const float cv = Cm[i * 4 + j];
#pragma unroll
            for (int p = 0; p < 2; ++p)
#pragma unroll
                for (int qq = 0; qq < 2; ++qq)
#pragma unroll
                    for (int rr = 0; rr < 2; ++rr)
#pragma unroll
                        for (int ss = 0; ss < 2; ++ss) {
                            const float cc = U1[m][p] * U1[kk][qq]
                                           * U1[nn][rr] * U1[ll][ss];
                            if (cc != 0.f)
                                Xc[p * 8 + qq * 4 + rr * 2 + ss] -= cv * cc;
                        }
        }
    }

    // ---------------- phase 2: eval 8 depths + softmax ---------------------
    const int d0 = q * 8;
    float c[8], dv[8];
    float mx = -INFINITY;
#pragma unroll
    for (int ck = 0; ck < 2; ++ck) {
        float pxs[2][4], pys[2][4];
#pragma unroll
        for (int dd = 0; dd < 4; ++dd) {
            const float depth = *(const float*)((const char*)dvals +
                                 (size_t)(d0 + ck * 4 + dd) * HW * 4 + voff);
            dv[ck * 4 + dd] = depth;
#pragma unroll
            for (int v = 0; v < 2; ++v) {
                float pxn = fmaf(rxv[v], depth, t0v[v]);
                float pyn = fmaf(ryv[v], depth, t1v[v]);
                float z   = fmaf(rzv[v], depth, t2v[v]);
                z = (fabsf(z) < 1e-6f) ? 1e-6f : z;
                float ri = frcp(z);
                pxs[v][dd] = pxn * ri;
                pys[v][dd] = pyn * ri;
            }
        }
#pragma unroll
        for (int dd = 0; dd < 4; ++dd) {
            float wx[2], wy[2];
            int ax0[2], ay0[2];
            bool fast = true;
#pragma unroll
            for (int v = 0; v < 2; ++v) {
                float px = pxs[v][dd], py = pys[v][dd];
                float x0f = floorf(px), y0f = floorf(py);
                wx[v] = px - x0f;
                wy[v] = py - y0f;
                int x0 = (int)x0f, y0 = (int)y0f;
                ax0[v] = x0; ay0[v] = y0;
                fast = fast && (x0 == x0r[v]) && (y0 == y0r[v]);
            }

            float cst;
            if (fast) {
                const float wx0 = wx[0], wy0 = wy[0];
                const float wx1 = wx[1], wy1 = wy[1];
                float a0 = fmaf(wy0, fmaf(wy0, A[2], A[1]), A[0]);
                float a1 = fmaf(wy0, fmaf(wy0, A[5], A[4]), A[3]);
                float a2 = fmaf(wy0, fmaf(wy0, A[8], A[7]), A[6]);
                float PA = fmaf(wx0, fmaf(wx0, a2, a1), a0);
                float b0 = fmaf(wy1, fmaf(wy1, Bp[2], Bp[1]), Bp[0]);
                float b1 = fmaf(wy1, fmaf(wy1, Bp[5], Bp[4]), Bp[3]);
                float b2 = fmaf(wy1, fmaf(wy1, Bp[8], Bp[7]), Bp[6]);
                float PB = fmaf(wx1, fmaf(wx1, b2, b1), b0);
                float y0_ = fmaf(wy1, Xc[1], Xc[0]);
                float y1_ = fmaf(wy1, Xc[3], Xc[2]);
                float y2_ = fmaf(wy1, Xc[5], Xc[4]);
                float y3_ = fmaf(wy1, Xc[7], Xc[6]);
                float y4_ = fmaf(wy1, Xc[9], Xc[8]);
                float y5_ = fmaf(wy1, Xc[11], Xc[10]);
                float y6_ = fmaf(wy1, Xc[13], Xc[12]);
                float y7_ = fmaf(wy1, Xc[15], Xc[14]);
                float z0_ = fmaf(wx1, y1_, y0_);
                float z1_ = fmaf(wx1, y3_, y2_);
                float z2_ = fmaf(wx1, y5_, y4_);
                float z3_ = fmaf(wx1, y7_, y6_);
                float w0_ = fmaf(wy0, z1_, z0_);
                float w1_ = fmaf(wy0, z3_, z2_);
                float Xv = fmaf(wx0, w1_, w0_);
                cst = (2.f / 9.f) * (PA + PB + Xv);
            } else {
                // slow path: exact direct regather with full mask logic
                float al[2][4];
                unsigned so[2][4];
#pragma unroll
                for (int v = 0; v < 2; ++v) {
                    int x0 = ax0[v], y0 = ay0[v];
                    bool vx0 = (x0 >= 0) && (x0 < NW);
                    bool vx1 = (x0 + 1 >= 0) && (x0 + 1 < NW);
                    bool vy0 = (y0 >= 0) && (y0 < NH);
                    bool vy1 = (y0 + 1 >= 0) && (y0 + 1 < NH);
                    float wxx = wx[v], wyy = wy[v];
                    al[v][0] = (1.f - wxx) * (1.f - wyy) * ((vx0 && vy0) ? 1.f : 0.f);
                    al[v][1] = wxx * (1.f - wyy) * ((vx1 && vy0) ? 1.f : 0.f);
                    al[v][2] = (1.f - wxx) * wyy * ((vx0 && vy1) ? 1.f : 0.f);
                    al[v][3] = wxx * wyy * ((vx1 && vy1) ? 1.f : 0.f);
                    int cx0 = min(max(x0, 0), NW - 1);
                    int cx1 = min(max(x0 + 1, 0), NW - 1);
                    int cy0 = min(max(y0, 0), NH - 1);
                    int cy1 = min(max(y0 + 1, 0), NH - 1);
                    so[v][0] = (unsigned)(cy0 * NW + cx0) * 4u;
                    so[v][1] = (unsigned)(cy0 * NW + cx1) * 4u;
                    so[v][2] = (unsigned)(cy1 * NW + cx0) * 4u;
                    so[v][3] = (unsigned)(cy1 * NW + cx1) * 4u;
                }
                float acc = 0.f;
#pragma unroll
                for (int cc = 0; cc < NC; ++cc) {
                    const char* frc = fb + (size_t)cc * HW * 4;
                    const char* f1c = f1b + (size_t)cc * HW * 4;
                    const char* f2c = f2b + (size_t)cc * HW * 4;
                    float r = *(const float*)(frc + voff);
                    float s1 = 0.f, s2 = 0.f;
#pragma unroll
                    for (int i = 0; i < 4; ++i) {
                        s1 = fmaf(*(const float*)(f1c + so[0][i]), al[0][i], s1);
                        s2 = fmaf(*(const float*)(f2c + so[1][i]), al[1][i], s2);
                    }
                    float e = r * r + s1 * s1 + s2 * s2
                            - r * s1 - r * s2 - s1 * s2;
                    acc = fmaf(wreg[cc], e, acc);
                }
                cst = (2.f / 9.f) * acc;
            }
            c[ck * 4 + dd] = cst;
            mx = fmaxf(mx, cst);
        }
    }

    // cross-lane softmax over the 4-lane group
    mx = fmaxf(mx, __shfl_xor(mx, 1));
    mx = fmaxf(mx, __shfl_xor(mx, 2));
    float ssum = 0.f;
#pragma unroll
    for (int i = 0; i < 8; ++i) {
        float e = expf(c[i] - mx);
        c[i] = e;
        ssum += e;
    }
    ssum += __shfl_xor(ssum, 1);
    ssum += __shfl_xor(ssum, 2);
    float inv = 1.f / ssum;

    float* prob = out + 2 * HW;
    float depth_acc = 0.f, didx_acc = 0.f;
#pragma unroll
    for (int i = 0; i < 8; ++i) {
        float pv = c[i] * inv;
        c[i] = pv;
        *(float*)((char*)prob + (size_t)(d0 + i) * HW * 4 + voff) = pv;
        depth_acc = fmaf(pv, dv[i], depth_acc);
        didx_acc = fmaf(pv, (float)(d0 + i), didx_acc);
    }
    depth_acc += __shfl_xor(depth_acc, 1);
    depth_acc += __shfl_xor(depth_acc, 2);
    didx_acc += __shfl_xor(didx_acc, 1);
    didx_acc += __shfl_xor(didx_acc, 2);

    int di = (int)didx_acc;            // trunc toward zero == astype(int32)
    di = min(max(di, 0), ND - 1);
    float pdi = 0.f, pdi1 = 0.f;
#pragma unroll
    for (int i = 0; i < 8; ++i) {
        pdi  = (d0 + i == di)     ? c[i] : pdi;
        pdi1 = (d0 + i == di + 1) ? c[i] : pdi1;
    }
    pdi  += __shfl_xor(pdi, 1);
    pdi  += __shfl_xor(pdi, 2);
    pdi1 += __shfl_xor(pdi1, 1);
    pdi1 += __shfl_xor(pdi1, 2);

    if (q == 0) {
        out[n] = depth_acc;
        out[HW + n] = pdi + pdi1;
    }
}

extern "C" void kernel_launch(void* const* d_in, const int* in_sizes, int n_in,
                              void* d_out, int out_size, void* d_ws, size_t ws_size,
                              hipStream_t stream) {
    const float* feats = (const float*)d_in[0];
    const float* pm    = (const float*)d_in[1];
    const float* dvals = (const float*)d_in[2];
    const float* wreg  = (const float*)d_in[3];
    float* out = (float*)d_out;
    (void)d_ws; (void)ws_size;

    mega_kernel<<<HW * 4 / 256, 256, 0, stream>>>(feats, pm, dvals, wreg, out);
}